// Round 1
// baseline (1203.733 us; speedup 1.0000x reference)
//
#include <hip/hip_runtime.h>
#include <hip/hip_bf16.h>
#include <math.h>

// Problem constants (match reference setup_inputs)
#define NN   100000
#define NE   1600000
#define FIN  128
#define HID  32
#define NHEADS 4
#define NCLS 10

// ---------------------------------------------------------------------------
// small utility kernels
// ---------------------------------------------------------------------------
__global__ void zero_i32(int* __restrict__ p, int n) {
    int i = blockIdx.x * blockDim.x + threadIdx.x;
    if (i < n) p[i] = 0;
}

__global__ void hist_kernel(const int* __restrict__ dst, int* __restrict__ cnt, int e) {
    int i = blockIdx.x * blockDim.x + threadIdx.x;
    if (i < e) atomicAdd(&cnt[dst[i]], 1);
}

// per-block sums of cnt (256 items / block)
__global__ void scan_block_sums(const int* __restrict__ cnt, int* __restrict__ bsum, int n) {
    __shared__ int sm[256];
    int i = blockIdx.x * 256 + threadIdx.x;
    int v = (i < n) ? cnt[i] : 0;
    sm[threadIdx.x] = v;
    __syncthreads();
    for (int off = 128; off > 0; off >>= 1) {
        if (threadIdx.x < off) sm[threadIdx.x] += sm[threadIdx.x + off];
        __syncthreads();
    }
    if (threadIdx.x == 0) bsum[blockIdx.x] = sm[0];
}

// single-block exclusive scan of block sums (nb <= 512)
__global__ void scan_single(const int* __restrict__ bsum, int* __restrict__ boff, int nb) {
    __shared__ int sm[512];
    int t = threadIdx.x;
    int v = (t < nb) ? bsum[t] : 0;
    sm[t] = v;
    __syncthreads();
    for (int off = 1; off < 512; off <<= 1) {
        int u = (t >= off) ? sm[t - off] : 0;
        __syncthreads();
        sm[t] += u;
        __syncthreads();
    }
    if (t < nb) boff[t] = sm[t] - v;   // exclusive
}

// in-block exclusive scan + add block offset -> rowptr
__global__ void scan_final(const int* __restrict__ cnt, const int* __restrict__ boff,
                           int* __restrict__ rowptr, int n) {
    __shared__ int sm[256];
    int i = blockIdx.x * 256 + threadIdx.x;
    int v = (i < n) ? cnt[i] : 0;
    sm[threadIdx.x] = v;
    __syncthreads();
    for (int off = 1; off < 256; off <<= 1) {
        int u = (threadIdx.x >= off) ? sm[threadIdx.x - off] : 0;
        __syncthreads();
        sm[threadIdx.x] += u;
        __syncthreads();
    }
    int incl = sm[threadIdx.x];
    int excl = incl - v;
    if (i < n) rowptr[i] = boff[blockIdx.x] + excl;
    if (i == n - 1) rowptr[n] = boff[blockIdx.x] + incl;  // == E
}

__global__ void scatter_kernel(const int* __restrict__ src, const int* __restrict__ dst,
                               const int* __restrict__ rowptr, int* __restrict__ cursor,
                               int* __restrict__ esrc, int e) {
    int i = blockIdx.x * blockDim.x + threadIdx.x;
    if (i < e) {
        int d = dst[i];
        int p = atomicAdd(&cursor[d], 1);
        esrc[rowptr[d] + p] = src[i];
    }
}

// ---------------------------------------------------------------------------
// GEMM: Out[n, FOUT] = X[n, 128] @ W[128, FOUT]   (fp32, register-blocked)
// ---------------------------------------------------------------------------
template <int FOUT>
__global__ __launch_bounds__(256) void gemm_k128(const float* __restrict__ X,
                                                 const float* __restrict__ Wm,
                                                 float* __restrict__ Out, int n) {
    constexpr int K   = 128;
    constexpr int RG  = 256 / FOUT;   // row-groups per block
    constexpr int RPT = 8;            // rows per thread
    constexpr int RPB = RG * RPT;     // rows per block
    const int col  = threadIdx.x % FOUT;
    const int rg   = threadIdx.x / FOUT;
    const int row0 = blockIdx.x * RPB + rg * RPT;

    const float* xp[RPT];
#pragma unroll
    for (int r = 0; r < RPT; ++r) {
        int rr = row0 + r;
        if (rr >= n) rr = n - 1;
        xp[r] = X + (size_t)rr * K;
    }
    float acc[RPT];
#pragma unroll
    for (int r = 0; r < RPT; ++r) acc[r] = 0.f;

    for (int k = 0; k < K; k += 4) {
        const float w0 = Wm[(k + 0) * FOUT + col];
        const float w1 = Wm[(k + 1) * FOUT + col];
        const float w2 = Wm[(k + 2) * FOUT + col];
        const float w3 = Wm[(k + 3) * FOUT + col];
#pragma unroll
        for (int r = 0; r < RPT; ++r) {
            const float4 xv = *(const float4*)(xp[r] + k);
            acc[r] = fmaf(xv.x, w0, fmaf(xv.y, w1, fmaf(xv.z, w2, fmaf(xv.w, w3, acc[r]))));
        }
    }
#pragma unroll
    for (int r = 0; r < RPT; ++r) {
        const int rr = row0 + r;
        if (rr < n) Out[(size_t)rr * FOUT + col] = acc[r];
    }
}

// ---------------------------------------------------------------------------
// attention logit tables: alS[n,h] = sum_c H[n,h,c]*a_src[h,c]; same for alD
// ---------------------------------------------------------------------------
template <int H, int C>
__global__ void al_kernel(const float* __restrict__ Hbuf, const float* __restrict__ a_s,
                          const float* __restrict__ a_d, float* __restrict__ alS,
                          float* __restrict__ alD, int n) {
    int t  = blockIdx.x * blockDim.x + threadIdx.x;
    int ni = t / H, h = t % H;
    if (ni >= n) return;
    const float* row = Hbuf + (size_t)ni * (H * C) + h * C;
    const float* asr = a_s + h * C;
    const float* adr = a_d + h * C;
    float s1 = 0.f, s2 = 0.f;
#pragma unroll
    for (int c = 0; c < C; c += 4) {
        float4 hv = *(const float4*)(row + c);
        float4 av = *(const float4*)(asr + c);
        float4 dv = *(const float4*)(adr + c);
        s1 += hv.x * av.x + hv.y * av.y + hv.z * av.z + hv.w * av.w;
        s2 += hv.x * dv.x + hv.y * dv.y + hv.z * dv.z + hv.w * dv.w;
    }
    alS[(size_t)ni * H + h] = s1;
    alD[(size_t)ni * H + h] = s2;
}

// ---------------------------------------------------------------------------
// wave-per-destination online-softmax aggregation + bias + BN + ELU
//   Out[d, :] = elu(bn( sum_e alpha_e * Hbuf[src_e, :] + bias ))
// ---------------------------------------------------------------------------
template <int H, int C>
__global__ __launch_bounds__(256) void gat_aggregate(
    const float* __restrict__ Hbuf, const int* __restrict__ rowptr,
    const int* __restrict__ esrc, const float* __restrict__ alS,
    const float* __restrict__ alD, const float* __restrict__ bias,
    const float* __restrict__ gamma, const float* __restrict__ beta,
    const float* __restrict__ bnmean, const float* __restrict__ bnvar,
    float* __restrict__ Out, int n) {
    constexpr int F = H * C;   // 128 or 32
    constexpr int NW = 4;      // waves per block
    __shared__ int   s_src[NW][64];
    __shared__ float s_ex[NW][64 * H];

    const int wave = threadIdx.x >> 6;
    const int lane = threadIdx.x & 63;
    const int d    = blockIdx.x * NW + wave;
    if (d >= n) return;                       // no block-level barriers used below

    const int beg = rowptr[d], end = rowptr[d + 1];
    float al_d[H], m[H], s[H];
#pragma unroll
    for (int h = 0; h < H; ++h) {
        al_d[h] = alD[(size_t)d * H + h];
        m[h]    = -INFINITY;
        s[h]    = 0.f;
    }
    float acc0 = 0.f, acc1 = 0.f;
    const int half = lane >> 5;   // 0 / 1

    for (int base = beg; base < end; base += 64) {
        const int j   = base + lane;
        const bool act = (j < end);
        int sj = 0;
        float e[H];
        if (act) {
            sj = esrc[j];
            if constexpr (H == 4) {
                float4 av = *(const float4*)(alS + (size_t)sj * 4);
                float t0 = av.x + al_d[0], t1 = av.y + al_d[1];
                float t2 = av.z + al_d[2], t3 = av.w + al_d[3];
                e[0] = t0 > 0.f ? t0 : 0.2f * t0;
                e[1] = t1 > 0.f ? t1 : 0.2f * t1;
                e[2] = t2 > 0.f ? t2 : 0.2f * t2;
                e[3] = t3 > 0.f ? t3 : 0.2f * t3;
            } else {
                float t0 = alS[sj] + al_d[0];
                e[0] = t0 > 0.f ? t0 : 0.2f * t0;
            }
        } else {
#pragma unroll
            for (int h = 0; h < H; ++h) e[h] = -INFINITY;
        }

        float scl[H];
#pragma unroll
        for (int h = 0; h < H; ++h) {
            float cm = e[h];
#pragma unroll
            for (int off = 32; off > 0; off >>= 1) cm = fmaxf(cm, __shfl_xor(cm, off));
            const float nm = fmaxf(m[h], cm);
            const float ex = act ? __expf(e[h] - nm) : 0.f;
            float cs = ex;
#pragma unroll
            for (int off = 32; off > 0; off >>= 1) cs += __shfl_xor(cs, off);
            scl[h] = __expf(m[h] - nm);       // 0 on first chunk (m=-inf)
            s[h]   = s[h] * scl[h] + cs;
            m[h]   = nm;
            s_ex[wave][lane * H + h] = ex;
        }
        if constexpr (F == 128) {
            acc0 *= (half == 0) ? scl[0] : scl[1];
            acc1 *= (half == 0) ? scl[2] : scl[3];
        } else {
            acc0 *= scl[0];
        }
        s_src[wave][lane] = sj;
        __builtin_amdgcn_wave_barrier();

        const int cc = min(64, end - base);
        for (int jj = 0; jj < cc; ++jj) {
            const int s0 = s_src[wave][jj];
            const float* hr = Hbuf + (size_t)s0 * F;
            if constexpr (F == 128) {
                const float wA = s_ex[wave][jj * H + half];
                const float wB = s_ex[wave][jj * H + 2 + half];
                acc0 = fmaf(hr[lane], wA, acc0);
                acc1 = fmaf(hr[64 + lane], wB, acc1);
            } else {
                const float wA = s_ex[wave][jj];
                acc0 = fmaf(hr[lane & 31], wA, acc0);
            }
        }
        __builtin_amdgcn_wave_barrier();
    }

    // epilogue: normalize, bias, BN, ELU
    if constexpr (F == 128) {
        const float sA = (half == 0) ? s[0] : s[1];
        const float sB = (half == 0) ? s[2] : s[3];
        const float o0 = acc0 / (sA + 1e-16f);
        const float o1 = acc1 / (sB + 1e-16f);
        const int c0 = lane, c1 = 64 + lane;
        float y0 = (o0 + bias[c0] - bnmean[c0]) * rsqrtf(bnvar[c0] + 1e-5f) * gamma[c0] + beta[c0];
        float y1 = (o1 + bias[c1] - bnmean[c1]) * rsqrtf(bnvar[c1] + 1e-5f) * gamma[c1] + beta[c1];
        y0 = y0 > 0.f ? y0 : expm1f(y0);
        y1 = y1 > 0.f ? y1 : expm1f(y1);
        Out[(size_t)d * 128 + c0] = y0;
        Out[(size_t)d * 128 + c1] = y1;
    } else {
        if (lane < 32) {
            const float o0 = acc0 / (s[0] + 1e-16f);
            const int c0 = lane;
            float y0 = (o0 + bias[c0] - bnmean[c0]) * rsqrtf(bnvar[c0] + 1e-5f) * gamma[c0] + beta[c0];
            y0 = y0 > 0.f ? y0 : expm1f(y0);
            Out[(size_t)d * 32 + c0] = y0;
        }
    }
}

// ---------------------------------------------------------------------------
// classifier: out[n, 10] = H3[n, 32] @ Wc[32, 10] + bc
// ---------------------------------------------------------------------------
__global__ void classifier_kernel(const float* __restrict__ H3, const float* __restrict__ Wc,
                                  const float* __restrict__ bc, float* __restrict__ out, int n) {
    int t  = blockIdx.x * blockDim.x + threadIdx.x;
    int ni = t / NCLS, c = t % NCLS;
    if (ni >= n) return;
    const float* row = H3 + (size_t)ni * HID;
    float a = bc[c];
#pragma unroll
    for (int k = 0; k < HID; ++k) a = fmaf(row[k], Wc[k * NCLS + c], a);
    out[(size_t)ni * NCLS + c] = a;
}

// ---------------------------------------------------------------------------
// launch
// ---------------------------------------------------------------------------
static inline char* align256(char* p) {
    return (char*)(((uintptr_t)p + 255) & ~(uintptr_t)255);
}

extern "C" void kernel_launch(void* const* d_in, const int* in_sizes, int n_in,
                              void* d_out, int out_size, void* d_ws, size_t ws_size,
                              hipStream_t stream) {
    const float* x  = (const float*)d_in[0];
    const int*   ei = (const int*)d_in[1];
    const int N = in_sizes[0] / FIN;
    const int E = in_sizes[1] / 2;
    const int* src = ei;
    const int* dst = ei + E;

    const float *W0 = (const float*)d_in[2],  *as0 = (const float*)d_in[3],
                *ad0 = (const float*)d_in[4], *b0 = (const float*)d_in[5],
                *g0 = (const float*)d_in[6],  *bt0 = (const float*)d_in[7],
                *m0 = (const float*)d_in[8],  *v0 = (const float*)d_in[9];
    const float *W1 = (const float*)d_in[10], *as1 = (const float*)d_in[11],
                *ad1 = (const float*)d_in[12],*b1 = (const float*)d_in[13],
                *g1 = (const float*)d_in[14], *bt1 = (const float*)d_in[15],
                *m1 = (const float*)d_in[16], *v1 = (const float*)d_in[17];
    const float *W2 = (const float*)d_in[18], *as2 = (const float*)d_in[19],
                *ad2 = (const float*)d_in[20],*b2 = (const float*)d_in[21],
                *g2 = (const float*)d_in[22], *bt2 = (const float*)d_in[23],
                *m2 = (const float*)d_in[24], *v2 = (const float*)d_in[25];
    const float *Wc = (const float*)d_in[26], *bc = (const float*)d_in[27];
    float* out = (float*)d_out;

    // workspace carve
    char* p = (char*)d_ws;
    float* A = (float*)p;       p = align256(p + (size_t)N * FIN * 4);   // gemm out
    float* B = (float*)p;       p = align256(p + (size_t)N * FIN * 4);   // layer act out
    float* alS = (float*)p;     p = align256(p + (size_t)N * NHEADS * 4);
    float* alD = (float*)p;     p = align256(p + (size_t)N * NHEADS * 4);
    int* cnt = (int*)p;         p = align256(p + (size_t)N * 4);
    int* cursor = (int*)p;      p = align256(p + (size_t)N * 4);
    int* rowptr = (int*)p;      p = align256(p + (size_t)(N + 1) * 4);
    int* esrc = (int*)p;        p = align256(p + (size_t)E * 4);
    int* bsum = (int*)p;        p = align256(p + 512 * 4);
    int* boff = (int*)p;        p = align256(p + 512 * 4);
    (void)ws_size; (void)n_in; (void)out_size;

    const int NB = (N + 255) / 256;   // 391 scan blocks

    // ---- CSR build (once; shared by all 3 layers) ----
    zero_i32<<<NB, 256, 0, stream>>>(cnt, N);
    zero_i32<<<NB, 256, 0, stream>>>(cursor, N);
    hist_kernel<<<(E + 255) / 256, 256, 0, stream>>>(dst, cnt, E);
    scan_block_sums<<<NB, 256, 0, stream>>>(cnt, bsum, N);
    scan_single<<<1, 512, 0, stream>>>(bsum, boff, NB);
    scan_final<<<NB, 256, 0, stream>>>(cnt, boff, rowptr, N);
    scatter_kernel<<<(E + 255) / 256, 256, 0, stream>>>(src, dst, rowptr, cursor, esrc, E);

    // ---- layer 0 ----
    gemm_k128<128><<<(N + 15) / 16, 256, 0, stream>>>(x, W0, A, N);
    al_kernel<4, 32><<<(N * 4 + 255) / 256, 256, 0, stream>>>(A, as0, ad0, alS, alD, N);
    gat_aggregate<4, 32><<<(N + 3) / 4, 256, 0, stream>>>(A, rowptr, esrc, alS, alD,
                                                          b0, g0, bt0, m0, v0, B, N);
    // ---- layer 1 ----
    gemm_k128<128><<<(N + 15) / 16, 256, 0, stream>>>(B, W1, A, N);
    al_kernel<4, 32><<<(N * 4 + 255) / 256, 256, 0, stream>>>(A, as1, ad1, alS, alD, N);
    gat_aggregate<4, 32><<<(N + 3) / 4, 256, 0, stream>>>(A, rowptr, esrc, alS, alD,
                                                          b1, g1, bt1, m1, v1, B, N);
    // ---- layer 2 (single head, C=32) ----
    gemm_k128<32><<<(N + 63) / 64, 256, 0, stream>>>(B, W2, A, N);
    al_kernel<1, 32><<<(N + 255) / 256, 256, 0, stream>>>(A, as2, ad2, alS, alD, N);
    gat_aggregate<1, 32><<<(N + 3) / 4, 256, 0, stream>>>(A, rowptr, esrc, alS, alD,
                                                          b2, g2, bt2, m2, v2, B, N);
    // ---- classifier ----
    classifier_kernel<<<(N * NCLS + 255) / 256, 256, 0, stream>>>(B, Wc, bc, out, N);
}

// Round 2
// 864.747 us; speedup vs baseline: 1.3920x; 1.3920x over previous
//
#include <hip/hip_runtime.h>
#include <hip/hip_bf16.h>
#include <math.h>

// Problem constants (match reference setup_inputs)
#define NN   100000
#define NE   1600000
#define FIN  128
#define HID  32
#define NHEADS 4
#define NCLS 10

// ---------------------------------------------------------------------------
// small utility kernels
// ---------------------------------------------------------------------------
__global__ void zero_i32(int* __restrict__ p, int n) {
    int i = blockIdx.x * blockDim.x + threadIdx.x;
    if (i < n) p[i] = 0;
}

__global__ void hist_kernel(const int* __restrict__ dst, int* __restrict__ cnt, int e) {
    int i = blockIdx.x * blockDim.x + threadIdx.x;
    if (i < e) atomicAdd(&cnt[dst[i]], 1);
}

// per-block sums of cnt (256 items / block)
__global__ void scan_block_sums(const int* __restrict__ cnt, int* __restrict__ bsum, int n) {
    __shared__ int sm[256];
    int i = blockIdx.x * 256 + threadIdx.x;
    int v = (i < n) ? cnt[i] : 0;
    sm[threadIdx.x] = v;
    __syncthreads();
    for (int off = 128; off > 0; off >>= 1) {
        if (threadIdx.x < off) sm[threadIdx.x] += sm[threadIdx.x + off];
        __syncthreads();
    }
    if (threadIdx.x == 0) bsum[blockIdx.x] = sm[0];
}

// single-block exclusive scan of block sums (nb <= 512)
__global__ void scan_single(const int* __restrict__ bsum, int* __restrict__ boff, int nb) {
    __shared__ int sm[512];
    int t = threadIdx.x;
    int v = (t < nb) ? bsum[t] : 0;
    sm[t] = v;
    __syncthreads();
    for (int off = 1; off < 512; off <<= 1) {
        int u = (t >= off) ? sm[t - off] : 0;
        __syncthreads();
        sm[t] += u;
        __syncthreads();
    }
    if (t < nb) boff[t] = sm[t] - v;   // exclusive
}

// in-block exclusive scan + add block offset -> rowptr
__global__ void scan_final(const int* __restrict__ cnt, const int* __restrict__ boff,
                           int* __restrict__ rowptr, int n) {
    __shared__ int sm[256];
    int i = blockIdx.x * 256 + threadIdx.x;
    int v = (i < n) ? cnt[i] : 0;
    sm[threadIdx.x] = v;
    __syncthreads();
    for (int off = 1; off < 256; off <<= 1) {
        int u = (threadIdx.x >= off) ? sm[threadIdx.x - off] : 0;
        __syncthreads();
        sm[threadIdx.x] += u;
        __syncthreads();
    }
    int incl = sm[threadIdx.x];
    int excl = incl - v;
    if (i < n) rowptr[i] = boff[blockIdx.x] + excl;
    if (i == n - 1) rowptr[n] = boff[blockIdx.x] + incl;  // == E
}

__global__ void scatter_kernel(const int* __restrict__ src, const int* __restrict__ dst,
                               const int* __restrict__ rowptr, int* __restrict__ cursor,
                               int* __restrict__ esrc, int e) {
    int i = blockIdx.x * blockDim.x + threadIdx.x;
    if (i < e) {
        int d = dst[i];
        int p = atomicAdd(&cursor[d], 1);
        esrc[rowptr[d] + p] = src[i];
    }
}

// ---------------------------------------------------------------------------
// LDS-tiled GEMM: Out[n, FOUT] = X[n, 128] @ W[128, FOUT]  (fp32)
// Block tile: 128 rows x FOUT cols, KC=32 staged in LDS.
// Micro-tile: 8 rows x (FOUT/16) cols per thread (256 threads).
// ---------------------------------------------------------------------------
template <int FOUT>
__global__ __launch_bounds__(256) void gemm_tiled(const float* __restrict__ X,
                                                  const float* __restrict__ Wm,
                                                  float* __restrict__ Out, int n) {
    constexpr int K   = 128;
    constexpr int KC  = 32;
    constexpr int MT  = 128;
    constexpr int CPT = FOUT / 16;            // 8 (FOUT=128) or 2 (FOUT=32)
    __shared__ float As[KC][MT + 1];          // [k][row], +1 pad vs write conflicts
    __shared__ float Bs[KC][FOUT];            // [k][col]

    const int t   = threadIdx.x;
    const int tx  = t & 15;                   // col group 0..15
    const int ty  = t >> 4;                   // row group 0..15
    const int row0 = blockIdx.x * MT;

    float acc[8][CPT];
#pragma unroll
    for (int i = 0; i < 8; ++i)
#pragma unroll
        for (int j = 0; j < CPT; ++j) acc[i][j] = 0.f;

    for (int kc = 0; kc < K; kc += KC) {
        // ---- load A tile: 128 rows x 32 k = 1024 float4, 4 per thread ----
#pragma unroll
        for (int i = 0; i < 4; ++i) {
            const int l  = t + i * 256;       // 0..1023
            const int ar = l >> 3;            // row in tile 0..127
            const int af = l & 7;             // float4 index within 32-k chunk
            int grow = row0 + ar;
            if (grow >= n) grow = n - 1;
            const float4 v = *(const float4*)(X + (size_t)grow * K + kc + af * 4);
            As[af * 4 + 0][ar] = v.x;
            As[af * 4 + 1][ar] = v.y;
            As[af * 4 + 2][ar] = v.z;
            As[af * 4 + 3][ar] = v.w;
        }
        // ---- load B tile: 32 k x FOUT cols ----
        constexpr int BF4 = KC * FOUT / 4;    // 1024 (FOUT=128) or 256 (FOUT=32)
#pragma unroll
        for (int i = 0; i < BF4 / 256; ++i) {
            const int l   = t + i * 256;
            const int br  = l / (FOUT / 4);   // k-row 0..31
            const int bc4 = l % (FOUT / 4);
            const float4 v = *(const float4*)(Wm + (size_t)(kc + br) * FOUT + bc4 * 4);
            *(float4*)&Bs[br][bc4 * 4] = v;
        }
        __syncthreads();

        // ---- compute ----
#pragma unroll 8
        for (int k = 0; k < KC; ++k) {
            float a[8], b[CPT];
#pragma unroll
            for (int i = 0; i < 8; ++i) a[i] = As[k][ty * 8 + i];
#pragma unroll
            for (int j = 0; j < CPT; ++j) b[j] = Bs[k][tx * CPT + j];
#pragma unroll
            for (int i = 0; i < 8; ++i)
#pragma unroll
                for (int j = 0; j < CPT; ++j)
                    acc[i][j] = fmaf(a[i], b[j], acc[i][j]);
        }
        __syncthreads();
    }

    // ---- store 8 rows x CPT cols per thread ----
#pragma unroll
    for (int i = 0; i < 8; ++i) {
        const int grow = row0 + ty * 8 + i;
        if (grow < n) {
            float* op = Out + (size_t)grow * FOUT + tx * CPT;
            if constexpr (CPT == 8) {
                float4 v0 = make_float4(acc[i][0], acc[i][1], acc[i][2], acc[i][3]);
                float4 v1 = make_float4(acc[i][4], acc[i][5], acc[i][6], acc[i][7]);
                *(float4*)(op + 0) = v0;
                *(float4*)(op + 4) = v1;
            } else {
                *(float2*)op = make_float2(acc[i][0], acc[i][1]);
            }
        }
    }
}

// ---------------------------------------------------------------------------
// attention logit tables: alS[n,h] = sum_c H[n,h,c]*a_src[h,c]; same for alD
// ---------------------------------------------------------------------------
template <int H, int C>
__global__ void al_kernel(const float* __restrict__ Hbuf, const float* __restrict__ a_s,
                          const float* __restrict__ a_d, float* __restrict__ alS,
                          float* __restrict__ alD, int n) {
    int t  = blockIdx.x * blockDim.x + threadIdx.x;
    int ni = t / H, h = t % H;
    if (ni >= n) return;
    const float* row = Hbuf + (size_t)ni * (H * C) + h * C;
    const float* asr = a_s + h * C;
    const float* adr = a_d + h * C;
    float s1 = 0.f, s2 = 0.f;
#pragma unroll
    for (int c = 0; c < C; c += 4) {
        float4 hv = *(const float4*)(row + c);
        float4 av = *(const float4*)(asr + c);
        float4 dv = *(const float4*)(adr + c);
        s1 += hv.x * av.x + hv.y * av.y + hv.z * av.z + hv.w * av.w;
        s2 += hv.x * dv.x + hv.y * dv.y + hv.z * dv.z + hv.w * dv.w;
    }
    alS[(size_t)ni * H + h] = s1;
    alD[(size_t)ni * H + h] = s2;
}

// ---------------------------------------------------------------------------
// wave-per-destination online-softmax aggregation + bias + BN + ELU
//   Out[d, :] = elu(bn( sum_e alpha_e * Hbuf[src_e, :] + bias ))
// ---------------------------------------------------------------------------
template <int H, int C>
__global__ __launch_bounds__(256) void gat_aggregate(
    const float* __restrict__ Hbuf, const int* __restrict__ rowptr,
    const int* __restrict__ esrc, const float* __restrict__ alS,
    const float* __restrict__ alD, const float* __restrict__ bias,
    const float* __restrict__ gamma, const float* __restrict__ beta,
    const float* __restrict__ bnmean, const float* __restrict__ bnvar,
    float* __restrict__ Out, int n) {
    constexpr int F = H * C;   // 128 or 32
    constexpr int NW = 4;      // waves per block
    __shared__ int   s_src[NW][64];
    __shared__ float s_ex[NW][64 * H];

    const int wave = threadIdx.x >> 6;
    const int lane = threadIdx.x & 63;
    const int d    = blockIdx.x * NW + wave;
    if (d >= n) return;                       // no block-level barriers used below

    const int beg = rowptr[d], end = rowptr[d + 1];
    float al_d[H], m[H], s[H];
#pragma unroll
    for (int h = 0; h < H; ++h) {
        al_d[h] = alD[(size_t)d * H + h];
        m[h]    = -INFINITY;
        s[h]    = 0.f;
    }
    float acc0 = 0.f, acc1 = 0.f;
    const int half = lane >> 5;   // 0 / 1

    for (int base = beg; base < end; base += 64) {
        const int j   = base + lane;
        const bool act = (j < end);
        int sj = 0;
        float e[H];
        if (act) {
            sj = esrc[j];
            if constexpr (H == 4) {
                float4 av = *(const float4*)(alS + (size_t)sj * 4);
                float t0 = av.x + al_d[0], t1 = av.y + al_d[1];
                float t2 = av.z + al_d[2], t3 = av.w + al_d[3];
                e[0] = t0 > 0.f ? t0 : 0.2f * t0;
                e[1] = t1 > 0.f ? t1 : 0.2f * t1;
                e[2] = t2 > 0.f ? t2 : 0.2f * t2;
                e[3] = t3 > 0.f ? t3 : 0.2f * t3;
            } else {
                float t0 = alS[sj] + al_d[0];
                e[0] = t0 > 0.f ? t0 : 0.2f * t0;
            }
        } else {
#pragma unroll
            for (int h = 0; h < H; ++h) e[h] = -INFINITY;
        }

        float scl[H];
#pragma unroll
        for (int h = 0; h < H; ++h) {
            float cm = e[h];
#pragma unroll
            for (int off = 32; off > 0; off >>= 1) cm = fmaxf(cm, __shfl_xor(cm, off));
            const float nm = fmaxf(m[h], cm);
            const float ex = act ? __expf(e[h] - nm) : 0.f;
            float cs = ex;
#pragma unroll
            for (int off = 32; off > 0; off >>= 1) cs += __shfl_xor(cs, off);
            scl[h] = __expf(m[h] - nm);       // 0 on first chunk (m=-inf)
            s[h]   = s[h] * scl[h] + cs;
            m[h]   = nm;
            s_ex[wave][lane * H + h] = ex;
        }
        if constexpr (F == 128) {
            acc0 *= (half == 0) ? scl[0] : scl[1];
            acc1 *= (half == 0) ? scl[2] : scl[3];
        } else {
            acc0 *= scl[0];
        }
        s_src[wave][lane] = sj;
        __builtin_amdgcn_wave_barrier();

        const int cc = min(64, end - base);
        for (int jj = 0; jj < cc; ++jj) {
            const int s0 = s_src[wave][jj];
            const float* hr = Hbuf + (size_t)s0 * F;
            if constexpr (F == 128) {
                const float wA = s_ex[wave][jj * H + half];
                const float wB = s_ex[wave][jj * H + 2 + half];
                acc0 = fmaf(hr[lane], wA, acc0);
                acc1 = fmaf(hr[64 + lane], wB, acc1);
            } else {
                const float wA = s_ex[wave][jj];
                acc0 = fmaf(hr[lane & 31], wA, acc0);
            }
        }
        __builtin_amdgcn_wave_barrier();
    }

    // epilogue: normalize, bias, BN, ELU
    if constexpr (F == 128) {
        const float sA = (half == 0) ? s[0] : s[1];
        const float sB = (half == 0) ? s[2] : s[3];
        const float o0 = acc0 / (sA + 1e-16f);
        const float o1 = acc1 / (sB + 1e-16f);
        const int c0 = lane, c1 = 64 + lane;
        float y0 = (o0 + bias[c0] - bnmean[c0]) * rsqrtf(bnvar[c0] + 1e-5f) * gamma[c0] + beta[c0];
        float y1 = (o1 + bias[c1] - bnmean[c1]) * rsqrtf(bnvar[c1] + 1e-5f) * gamma[c1] + beta[c1];
        y0 = y0 > 0.f ? y0 : expm1f(y0);
        y1 = y1 > 0.f ? y1 : expm1f(y1);
        Out[(size_t)d * 128 + c0] = y0;
        Out[(size_t)d * 128 + c1] = y1;
    } else {
        if (lane < 32) {
            const float o0 = acc0 / (s[0] + 1e-16f);
            const int c0 = lane;
            float y0 = (o0 + bias[c0] - bnmean[c0]) * rsqrtf(bnvar[c0] + 1e-5f) * gamma[c0] + beta[c0];
            y0 = y0 > 0.f ? y0 : expm1f(y0);
            Out[(size_t)d * 32 + c0] = y0;
        }
    }
}

// ---------------------------------------------------------------------------
// classifier: out[n, 10] = H3[n, 32] @ Wc[32, 10] + bc
// ---------------------------------------------------------------------------
__global__ void classifier_kernel(const float* __restrict__ H3, const float* __restrict__ Wc,
                                  const float* __restrict__ bc, float* __restrict__ out, int n) {
    int t  = blockIdx.x * blockDim.x + threadIdx.x;
    int ni = t / NCLS, c = t % NCLS;
    if (ni >= n) return;
    const float* row = H3 + (size_t)ni * HID;
    float a = bc[c];
#pragma unroll
    for (int k = 0; k < HID; ++k) a = fmaf(row[k], Wc[k * NCLS + c], a);
    out[(size_t)ni * NCLS + c] = a;
}

// ---------------------------------------------------------------------------
// launch
// ---------------------------------------------------------------------------
static inline char* align256(char* p) {
    return (char*)(((uintptr_t)p + 255) & ~(uintptr_t)255);
}

extern "C" void kernel_launch(void* const* d_in, const int* in_sizes, int n_in,
                              void* d_out, int out_size, void* d_ws, size_t ws_size,
                              hipStream_t stream) {
    const float* x  = (const float*)d_in[0];
    const int*   ei = (const int*)d_in[1];
    const int N = in_sizes[0] / FIN;
    const int E = in_sizes[1] / 2;
    const int* src = ei;
    const int* dst = ei + E;

    const float *W0 = (const float*)d_in[2],  *as0 = (const float*)d_in[3],
                *ad0 = (const float*)d_in[4], *b0 = (const float*)d_in[5],
                *g0 = (const float*)d_in[6],  *bt0 = (const float*)d_in[7],
                *m0 = (const float*)d_in[8],  *v0 = (const float*)d_in[9];
    const float *W1 = (const float*)d_in[10], *as1 = (const float*)d_in[11],
                *ad1 = (const float*)d_in[12],*b1 = (const float*)d_in[13],
                *g1 = (const float*)d_in[14], *bt1 = (const float*)d_in[15],
                *m1 = (const float*)d_in[16], *v1 = (const float*)d_in[17];
    const float *W2 = (const float*)d_in[18], *as2 = (const float*)d_in[19],
                *ad2 = (const float*)d_in[20],*b2 = (const float*)d_in[21],
                *g2 = (const float*)d_in[22], *bt2 = (const float*)d_in[23],
                *m2 = (const float*)d_in[24], *v2 = (const float*)d_in[25];
    const float *Wc = (const float*)d_in[26], *bc = (const float*)d_in[27];
    float* out = (float*)d_out;

    // workspace carve
    char* p = (char*)d_ws;
    float* A = (float*)p;       p = align256(p + (size_t)N * FIN * 4);   // gemm out
    float* B = (float*)p;       p = align256(p + (size_t)N * FIN * 4);   // layer act out
    float* alS = (float*)p;     p = align256(p + (size_t)N * NHEADS * 4);
    float* alD = (float*)p;     p = align256(p + (size_t)N * NHEADS * 4);
    int* cnt = (int*)p;         p = align256(p + (size_t)N * 4);
    int* cursor = (int*)p;      p = align256(p + (size_t)N * 4);
    int* rowptr = (int*)p;      p = align256(p + (size_t)(N + 1) * 4);
    int* esrc = (int*)p;        p = align256(p + (size_t)E * 4);
    int* bsum = (int*)p;        p = align256(p + 512 * 4);
    int* boff = (int*)p;        p = align256(p + 512 * 4);
    (void)ws_size; (void)n_in; (void)out_size;

    const int NB = (N + 255) / 256;   // 391 scan blocks

    // ---- CSR build (once; shared by all 3 layers) ----
    zero_i32<<<NB, 256, 0, stream>>>(cnt, N);
    zero_i32<<<NB, 256, 0, stream>>>(cursor, N);
    hist_kernel<<<(E + 255) / 256, 256, 0, stream>>>(dst, cnt, E);
    scan_block_sums<<<NB, 256, 0, stream>>>(cnt, bsum, N);
    scan_single<<<1, 512, 0, stream>>>(bsum, boff, NB);
    scan_final<<<NB, 256, 0, stream>>>(cnt, boff, rowptr, N);
    scatter_kernel<<<(E + 255) / 256, 256, 0, stream>>>(src, dst, rowptr, cursor, esrc, E);

    const int GB = (N + 127) / 128;   // gemm blocks

    // ---- layer 0 ----
    gemm_tiled<128><<<GB, 256, 0, stream>>>(x, W0, A, N);
    al_kernel<4, 32><<<(N * 4 + 255) / 256, 256, 0, stream>>>(A, as0, ad0, alS, alD, N);
    gat_aggregate<4, 32><<<(N + 3) / 4, 256, 0, stream>>>(A, rowptr, esrc, alS, alD,
                                                          b0, g0, bt0, m0, v0, B, N);
    // ---- layer 1 ----
    gemm_tiled<128><<<GB, 256, 0, stream>>>(B, W1, A, N);
    al_kernel<4, 32><<<(N * 4 + 255) / 256, 256, 0, stream>>>(A, as1, ad1, alS, alD, N);
    gat_aggregate<4, 32><<<(N + 3) / 4, 256, 0, stream>>>(A, rowptr, esrc, alS, alD,
                                                          b1, g1, bt1, m1, v1, B, N);
    // ---- layer 2 (single head, C=32) ----
    gemm_tiled<32><<<GB, 256, 0, stream>>>(B, W2, A, N);
    al_kernel<1, 32><<<(N + 255) / 256, 256, 0, stream>>>(A, as2, ad2, alS, alD, N);
    gat_aggregate<1, 32><<<(N + 3) / 4, 256, 0, stream>>>(A, rowptr, esrc, alS, alD,
                                                          b2, g2, bt2, m2, v2, B, N);
    // ---- classifier ----
    classifier_kernel<<<(N * NCLS + 255) / 256, 256, 0, stream>>>(B, Wc, bc, out, N);
}

// Round 3
// 704.043 us; speedup vs baseline: 1.7097x; 1.2283x over previous
//
#include <hip/hip_runtime.h>
#include <hip/hip_bf16.h>
#include <math.h>

// Problem constants (match reference setup_inputs)
#define NN   100000
#define NE   1600000
#define FIN  128
#define HID  32
#define NHEADS 4
#define NCLS 10

typedef unsigned int uint32;

__device__ __forceinline__ float bf_lo(uint32 v) {
    return __builtin_bit_cast(float, v << 16);
}
__device__ __forceinline__ float bf_hi(uint32 v) {
    return __builtin_bit_cast(float, v & 0xffff0000u);
}
__device__ __forceinline__ uint32 packbf2(float a, float b) {
    uint32 ua = __builtin_bit_cast(uint32, a);
    uint32 ub = __builtin_bit_cast(uint32, b);
    ua = (ua + 0x7fffu + ((ua >> 16) & 1u)) >> 16;          // RNE
    ub = (ub + 0x7fffu + ((ub >> 16) & 1u)) & 0xffff0000u;  // RNE, keep high
    return ua | ub;
}

// ---------------------------------------------------------------------------
// small utility kernels
// ---------------------------------------------------------------------------
__global__ void zero_i32(int* __restrict__ p, int n) {
    int i = blockIdx.x * blockDim.x + threadIdx.x;
    if (i < n) p[i] = 0;
}

__global__ void hist_kernel(const int* __restrict__ dst, int* __restrict__ cnt, int e) {
    int i = blockIdx.x * blockDim.x + threadIdx.x;
    if (i < e) atomicAdd(&cnt[dst[i]], 1);
}

__global__ void scan_block_sums(const int* __restrict__ cnt, int* __restrict__ bsum, int n) {
    __shared__ int sm[256];
    int i = blockIdx.x * 256 + threadIdx.x;
    int v = (i < n) ? cnt[i] : 0;
    sm[threadIdx.x] = v;
    __syncthreads();
    for (int off = 128; off > 0; off >>= 1) {
        if (threadIdx.x < off) sm[threadIdx.x] += sm[threadIdx.x + off];
        __syncthreads();
    }
    if (threadIdx.x == 0) bsum[blockIdx.x] = sm[0];
}

__global__ void scan_single(const int* __restrict__ bsum, int* __restrict__ boff, int nb) {
    __shared__ int sm[512];
    int t = threadIdx.x;
    int v = (t < nb) ? bsum[t] : 0;
    sm[t] = v;
    __syncthreads();
    for (int off = 1; off < 512; off <<= 1) {
        int u = (t >= off) ? sm[t - off] : 0;
        __syncthreads();
        sm[t] += u;
        __syncthreads();
    }
    if (t < nb) boff[t] = sm[t] - v;   // exclusive
}

__global__ void scan_final(const int* __restrict__ cnt, const int* __restrict__ boff,
                           int* __restrict__ rowptr, int n) {
    __shared__ int sm[256];
    int i = blockIdx.x * 256 + threadIdx.x;
    int v = (i < n) ? cnt[i] : 0;
    sm[threadIdx.x] = v;
    __syncthreads();
    for (int off = 1; off < 256; off <<= 1) {
        int u = (threadIdx.x >= off) ? sm[threadIdx.x - off] : 0;
        __syncthreads();
        sm[threadIdx.x] += u;
        __syncthreads();
    }
    int incl = sm[threadIdx.x];
    int excl = incl - v;
    if (i < n) rowptr[i] = boff[blockIdx.x] + excl;
    if (i == n - 1) rowptr[n] = boff[blockIdx.x] + incl;  // == E
}

__global__ void scatter_kernel(const int* __restrict__ src, const int* __restrict__ dst,
                               const int* __restrict__ rowptr, int* __restrict__ cursor,
                               int* __restrict__ esrc, int e) {
    int i = blockIdx.x * blockDim.x + threadIdx.x;
    if (i < e) {
        int d = dst[i];
        int p = atomicAdd(&cursor[d], 1);
        esrc[rowptr[d] + p] = src[i];
    }
}

// ---------------------------------------------------------------------------
// LDS-tiled GEMM: Out[n, FOUT] = X[n, 128] @ W[128, FOUT]  (fp32)
// Also writes a bf16-packed copy of the output (for the edge gather).
// ---------------------------------------------------------------------------
template <int FOUT>
__global__ __launch_bounds__(256) void gemm_tiled(const float* __restrict__ X,
                                                  const float* __restrict__ Wm,
                                                  float* __restrict__ Out,
                                                  uint32* __restrict__ Outb, int n) {
    constexpr int K   = 128;
    constexpr int KC  = 32;
    constexpr int MT  = 128;
    constexpr int CPT = FOUT / 16;            // 8 (FOUT=128) or 2 (FOUT=32)
    __shared__ float As[KC][MT + 1];
    __shared__ float Bs[KC][FOUT];

    const int t   = threadIdx.x;
    const int tx  = t & 15;
    const int ty  = t >> 4;
    const int row0 = blockIdx.x * MT;

    float acc[8][CPT];
#pragma unroll
    for (int i = 0; i < 8; ++i)
#pragma unroll
        for (int j = 0; j < CPT; ++j) acc[i][j] = 0.f;

    for (int kc = 0; kc < K; kc += KC) {
#pragma unroll
        for (int i = 0; i < 4; ++i) {
            const int l  = t + i * 256;
            const int ar = l >> 3;
            const int af = l & 7;
            int grow = row0 + ar;
            if (grow >= n) grow = n - 1;
            const float4 v = *(const float4*)(X + (size_t)grow * K + kc + af * 4);
            As[af * 4 + 0][ar] = v.x;
            As[af * 4 + 1][ar] = v.y;
            As[af * 4 + 2][ar] = v.z;
            As[af * 4 + 3][ar] = v.w;
        }
        constexpr int BF4 = KC * FOUT / 4;
#pragma unroll
        for (int i = 0; i < BF4 / 256; ++i) {
            const int l   = t + i * 256;
            const int br  = l / (FOUT / 4);
            const int bc4 = l % (FOUT / 4);
            const float4 v = *(const float4*)(Wm + (size_t)(kc + br) * FOUT + bc4 * 4);
            *(float4*)&Bs[br][bc4 * 4] = v;
        }
        __syncthreads();

#pragma unroll 8
        for (int k = 0; k < KC; ++k) {
            float a[8], b[CPT];
#pragma unroll
            for (int i = 0; i < 8; ++i) a[i] = As[k][ty * 8 + i];
#pragma unroll
            for (int j = 0; j < CPT; ++j) b[j] = Bs[k][tx * CPT + j];
#pragma unroll
            for (int i = 0; i < 8; ++i)
#pragma unroll
                for (int j = 0; j < CPT; ++j)
                    acc[i][j] = fmaf(a[i], b[j], acc[i][j]);
        }
        __syncthreads();
    }

#pragma unroll
    for (int i = 0; i < 8; ++i) {
        const int grow = row0 + ty * 8 + i;
        if (grow < n) {
            float* op = Out + (size_t)grow * FOUT + tx * CPT;
            uint32* bp = Outb + ((size_t)grow * FOUT + tx * CPT) / 2;
            if constexpr (CPT == 8) {
                *(float4*)(op + 0) = make_float4(acc[i][0], acc[i][1], acc[i][2], acc[i][3]);
                *(float4*)(op + 4) = make_float4(acc[i][4], acc[i][5], acc[i][6], acc[i][7]);
                uint4 pb;
                pb.x = packbf2(acc[i][0], acc[i][1]);
                pb.y = packbf2(acc[i][2], acc[i][3]);
                pb.z = packbf2(acc[i][4], acc[i][5]);
                pb.w = packbf2(acc[i][6], acc[i][7]);
                *(uint4*)bp = pb;
            } else {
                *(float2*)op = make_float2(acc[i][0], acc[i][1]);
                *bp = packbf2(acc[i][0], acc[i][1]);
            }
        }
    }
}

// ---------------------------------------------------------------------------
// attention logit tables: alS[n,h] = sum_c H[n,h,c]*a_src[h,c]; same for alD
// ---------------------------------------------------------------------------
template <int H, int C>
__global__ void al_kernel(const float* __restrict__ Hbuf, const float* __restrict__ a_s,
                          const float* __restrict__ a_d, float* __restrict__ alS,
                          float* __restrict__ alD, int n) {
    int t  = blockIdx.x * blockDim.x + threadIdx.x;
    int ni = t / H, h = t % H;
    if (ni >= n) return;
    const float* row = Hbuf + (size_t)ni * (H * C) + h * C;
    const float* asr = a_s + h * C;
    const float* adr = a_d + h * C;
    float s1 = 0.f, s2 = 0.f;
#pragma unroll
    for (int c = 0; c < C; c += 4) {
        float4 hv = *(const float4*)(row + c);
        float4 av = *(const float4*)(asr + c);
        float4 dv = *(const float4*)(adr + c);
        s1 += hv.x * av.x + hv.y * av.y + hv.z * av.z + hv.w * av.w;
        s2 += hv.x * dv.x + hv.y * dv.y + hv.z * dv.z + hv.w * dv.w;
    }
    alS[(size_t)ni * H + h] = s1;
    alD[(size_t)ni * H + h] = s2;
}

// ---------------------------------------------------------------------------
// wave-per-destination aggregation (no-max softmax, bf16 gather) + BN + ELU
//   Out[d, :] = elu(bn( sum_e softmax(e)_e * h[src_e, :] + bias ))
// Logits are bounded (|e| <~ 10) so exp() without max subtraction is safe and
// mathematically identical to the max-subtracted softmax.
// ---------------------------------------------------------------------------
template <int H, int C>
__global__ __launch_bounds__(256) void gat_aggregate(
    const uint32* __restrict__ Hb,            // bf16-packed h, row = H*C/2 uints
    const int* __restrict__ rowptr, const int* __restrict__ esrc,
    const float* __restrict__ alS, const float* __restrict__ alD,
    const float* __restrict__ bias, const float* __restrict__ gamma,
    const float* __restrict__ beta, const float* __restrict__ bnmean,
    const float* __restrict__ bnvar, float* __restrict__ Out, int n) {
    constexpr int F  = H * C;                 // 128 or 32
    constexpr int RW = F / 2;                 // uints per row: 64 or 16
    constexpr int NW = 4;
    __shared__ int   s_src[NW][64];
    __shared__ float s_ex[NW][H][64];         // [head][edge-slot]: stride-1 writes

    const int wave = threadIdx.x >> 6;
    const int lane = threadIdx.x & 63;
    const int d    = blockIdx.x * NW + wave;
    if (d >= n) return;                       // only wave-level barriers below

    const int beg = rowptr[d], end = rowptr[d + 1];
    float al_d[H], sl[H];
#pragma unroll
    for (int h = 0; h < H; ++h) {
        al_d[h] = alD[(size_t)d * H + h];
        sl[h]   = 0.f;
    }
    float acc0 = 0.f, acc1 = 0.f;
    const int head = (H == 4) ? (lane >> 4) : 0;       // 2 channels per lane
    const int li   = (F == 128) ? lane : (lane & 15);  // uint index within row

    for (int base = beg; base < end; base += 64) {
        const int j   = base + lane;
        const bool act = (j < end);
        int sj = 0;
        float ex[H];
        if (act) {
            sj = esrc[j];
            if constexpr (H == 4) {
                float4 av = *(const float4*)(alS + (size_t)sj * 4);
                float t0 = av.x + al_d[0], t1 = av.y + al_d[1];
                float t2 = av.z + al_d[2], t3 = av.w + al_d[3];
                t0 = t0 > 0.f ? t0 : 0.2f * t0;
                t1 = t1 > 0.f ? t1 : 0.2f * t1;
                t2 = t2 > 0.f ? t2 : 0.2f * t2;
                t3 = t3 > 0.f ? t3 : 0.2f * t3;
                ex[0] = __expf(t0); ex[1] = __expf(t1);
                ex[2] = __expf(t2); ex[3] = __expf(t3);
            } else {
                float t0 = alS[sj] + al_d[0];
                t0 = t0 > 0.f ? t0 : 0.2f * t0;
                ex[0] = __expf(t0);
            }
        } else {
#pragma unroll
            for (int h = 0; h < H; ++h) ex[h] = 0.f;
        }
#pragma unroll
        for (int h = 0; h < H; ++h) {
            s_ex[wave][h][lane] = ex[h];
            sl[h] += ex[h];
        }
        s_src[wave][lane] = sj;
        __builtin_amdgcn_wave_barrier();

        const int cc = min(64, end - base);
#pragma unroll 4
        for (int jj = 0; jj < cc; ++jj) {
            const int s0 = s_src[wave][jj];
            const float w = s_ex[wave][head][jj];
            const uint32 v = Hb[(size_t)s0 * RW + li];
            acc0 = fmaf(bf_lo(v), w, acc0);
            acc1 = fmaf(bf_hi(v), w, acc1);
        }
        __builtin_amdgcn_wave_barrier();
    }

    // one wave reduction of the exp-sums (inactive lanes contributed 0)
#pragma unroll
    for (int h = 0; h < H; ++h) {
#pragma unroll
        for (int off = 32; off > 0; off >>= 1) sl[h] += __shfl_xor(sl[h], off);
    }
    float sh;
    if constexpr (H == 4) {
        float a = (head & 1) ? sl[1] : sl[0];
        float b = (head & 1) ? sl[3] : sl[2];
        sh = (head & 2) ? b : a;
    } else {
        sh = sl[0];
    }

    const float inv = 1.f / (sh + 1e-16f);
    const int c0 = 2 * li, c1 = 2 * li + 1;
    const bool wr = (F == 128) || (lane < 16);
    if (wr) {
        float o0 = acc0 * inv, o1 = acc1 * inv;
        float y0 = (o0 + bias[c0] - bnmean[c0]) * rsqrtf(bnvar[c0] + 1e-5f) * gamma[c0] + beta[c0];
        float y1 = (o1 + bias[c1] - bnmean[c1]) * rsqrtf(bnvar[c1] + 1e-5f) * gamma[c1] + beta[c1];
        y0 = y0 > 0.f ? y0 : expm1f(y0);
        y1 = y1 > 0.f ? y1 : expm1f(y1);
        *(float2*)(Out + (size_t)d * F + c0) = make_float2(y0, y1);
    }
}

// ---------------------------------------------------------------------------
// classifier: out[n, 10] = H3[n, 32] @ Wc[32, 10] + bc
// ---------------------------------------------------------------------------
__global__ void classifier_kernel(const float* __restrict__ H3, const float* __restrict__ Wc,
                                  const float* __restrict__ bc, float* __restrict__ out, int n) {
    int t  = blockIdx.x * blockDim.x + threadIdx.x;
    int ni = t / NCLS, c = t % NCLS;
    if (ni >= n) return;
    const float* row = H3 + (size_t)ni * HID;
    float a = bc[c];
#pragma unroll
    for (int k = 0; k < HID; ++k) a = fmaf(row[k], Wc[k * NCLS + c], a);
    out[(size_t)ni * NCLS + c] = a;
}

// ---------------------------------------------------------------------------
// launch
// ---------------------------------------------------------------------------
static inline char* align256(char* p) {
    return (char*)(((uintptr_t)p + 255) & ~(uintptr_t)255);
}

extern "C" void kernel_launch(void* const* d_in, const int* in_sizes, int n_in,
                              void* d_out, int out_size, void* d_ws, size_t ws_size,
                              hipStream_t stream) {
    const float* x  = (const float*)d_in[0];
    const int*   ei = (const int*)d_in[1];
    const int N = in_sizes[0] / FIN;
    const int E = in_sizes[1] / 2;
    const int* src = ei;
    const int* dst = ei + E;

    const float *W0 = (const float*)d_in[2],  *as0 = (const float*)d_in[3],
                *ad0 = (const float*)d_in[4], *b0 = (const float*)d_in[5],
                *g0 = (const float*)d_in[6],  *bt0 = (const float*)d_in[7],
                *m0 = (const float*)d_in[8],  *v0 = (const float*)d_in[9];
    const float *W1 = (const float*)d_in[10], *as1 = (const float*)d_in[11],
                *ad1 = (const float*)d_in[12],*b1 = (const float*)d_in[13],
                *g1 = (const float*)d_in[14], *bt1 = (const float*)d_in[15],
                *m1 = (const float*)d_in[16], *v1 = (const float*)d_in[17];
    const float *W2 = (const float*)d_in[18], *as2 = (const float*)d_in[19],
                *ad2 = (const float*)d_in[20],*b2 = (const float*)d_in[21],
                *g2 = (const float*)d_in[22], *bt2 = (const float*)d_in[23],
                *m2 = (const float*)d_in[24], *v2 = (const float*)d_in[25];
    const float *Wc = (const float*)d_in[26], *bc = (const float*)d_in[27];
    float* out = (float*)d_out;

    // workspace carve
    char* p = (char*)d_ws;
    float* A = (float*)p;       p = align256(p + (size_t)N * FIN * 4);   // gemm out fp32
    uint32* Abf = (uint32*)p;   p = align256(p + (size_t)N * FIN * 2);   // gemm out bf16
    float* B = (float*)p;       p = align256(p + (size_t)N * FIN * 4);   // layer act out
    float* alS = (float*)p;     p = align256(p + (size_t)N * NHEADS * 4);
    float* alD = (float*)p;     p = align256(p + (size_t)N * NHEADS * 4);
    int* cnt = (int*)p;         p = align256(p + (size_t)N * 4);
    int* cursor = (int*)p;      p = align256(p + (size_t)N * 4);
    int* rowptr = (int*)p;      p = align256(p + (size_t)(N + 1) * 4);
    int* esrc = (int*)p;        p = align256(p + (size_t)E * 4);
    int* bsum = (int*)p;        p = align256(p + 512 * 4);
    int* boff = (int*)p;        p = align256(p + 512 * 4);
    (void)ws_size; (void)n_in; (void)out_size;

    const int NB = (N + 255) / 256;

    // ---- CSR build (once; shared by all 3 layers) ----
    zero_i32<<<NB, 256, 0, stream>>>(cnt, N);
    zero_i32<<<NB, 256, 0, stream>>>(cursor, N);
    hist_kernel<<<(E + 255) / 256, 256, 0, stream>>>(dst, cnt, E);
    scan_block_sums<<<NB, 256, 0, stream>>>(cnt, bsum, N);
    scan_single<<<1, 512, 0, stream>>>(bsum, boff, NB);
    scan_final<<<NB, 256, 0, stream>>>(cnt, boff, rowptr, N);
    scatter_kernel<<<(E + 255) / 256, 256, 0, stream>>>(src, dst, rowptr, cursor, esrc, E);

    const int GB = (N + 127) / 128;

    // ---- layer 0 ----
    gemm_tiled<128><<<GB, 256, 0, stream>>>(x, W0, A, Abf, N);
    al_kernel<4, 32><<<(N * 4 + 255) / 256, 256, 0, stream>>>(A, as0, ad0, alS, alD, N);
    gat_aggregate<4, 32><<<(N + 3) / 4, 256, 0, stream>>>(Abf, rowptr, esrc, alS, alD,
                                                          b0, g0, bt0, m0, v0, B, N);
    // ---- layer 1 ----
    gemm_tiled<128><<<GB, 256, 0, stream>>>(B, W1, A, Abf, N);
    al_kernel<4, 32><<<(N * 4 + 255) / 256, 256, 0, stream>>>(A, as1, ad1, alS, alD, N);
    gat_aggregate<4, 32><<<(N + 3) / 4, 256, 0, stream>>>(Abf, rowptr, esrc, alS, alD,
                                                          b1, g1, bt1, m1, v1, B, N);
    // ---- layer 2 (single head, C=32) ----
    gemm_tiled<32><<<GB, 256, 0, stream>>>(B, W2, A, Abf, N);
    al_kernel<1, 32><<<(N + 255) / 256, 256, 0, stream>>>(A, as2, ad2, alS, alD, N);
    gat_aggregate<1, 32><<<(N + 3) / 4, 256, 0, stream>>>(Abf, rowptr, esrc, alS, alD,
                                                          b2, g2, bt2, m2, v2, B, N);
    // ---- classifier ----
    classifier_kernel<<<(N * NCLS + 255) / 256, 256, 0, stream>>>(B, Wc, bc, out, N);
}

// Round 4
// 666.095 us; speedup vs baseline: 1.8072x; 1.0570x over previous
//
#include <hip/hip_runtime.h>
#include <hip/hip_bf16.h>
#include <math.h>

// Problem constants (match reference setup_inputs)
#define NN   100000
#define NE   1600000
#define FIN  128
#define HID  32
#define NHEADS 4
#define NCLS 10

typedef unsigned int uint32;

__device__ __forceinline__ float bf_lo(uint32 v) {
    return __builtin_bit_cast(float, v << 16);
}
__device__ __forceinline__ float bf_hi(uint32 v) {
    return __builtin_bit_cast(float, v & 0xffff0000u);
}
__device__ __forceinline__ uint32 packbf2(float a, float b) {
    uint32 ua = __builtin_bit_cast(uint32, a);
    uint32 ub = __builtin_bit_cast(uint32, b);
    ua = (ua + 0x7fffu + ((ua >> 16) & 1u)) >> 16;          // RNE
    ub = (ub + 0x7fffu + ((ub >> 16) & 1u)) & 0xffff0000u;  // RNE, keep high
    return ua | ub;
}

// ---------------------------------------------------------------------------
// small utility kernels (CSR build)
// ---------------------------------------------------------------------------
__global__ void zero_i32(int* __restrict__ p, int n) {
    int i = blockIdx.x * blockDim.x + threadIdx.x;
    if (i < n) p[i] = 0;
}

__global__ void hist_kernel(const int* __restrict__ dst, int* __restrict__ cnt, int e) {
    int i = blockIdx.x * blockDim.x + threadIdx.x;
    if (i < e) atomicAdd(&cnt[dst[i]], 1);
}

__global__ void scan_block_sums(const int* __restrict__ cnt, int* __restrict__ bsum, int n) {
    __shared__ int sm[256];
    int i = blockIdx.x * 256 + threadIdx.x;
    int v = (i < n) ? cnt[i] : 0;
    sm[threadIdx.x] = v;
    __syncthreads();
    for (int off = 128; off > 0; off >>= 1) {
        if (threadIdx.x < off) sm[threadIdx.x] += sm[threadIdx.x + off];
        __syncthreads();
    }
    if (threadIdx.x == 0) bsum[blockIdx.x] = sm[0];
}

__global__ void scan_single(const int* __restrict__ bsum, int* __restrict__ boff, int nb) {
    __shared__ int sm[512];
    int t = threadIdx.x;
    int v = (t < nb) ? bsum[t] : 0;
    sm[t] = v;
    __syncthreads();
    for (int off = 1; off < 512; off <<= 1) {
        int u = (t >= off) ? sm[t - off] : 0;
        __syncthreads();
        sm[t] += u;
        __syncthreads();
    }
    if (t < nb) boff[t] = sm[t] - v;   // exclusive
}

__global__ void scan_final(const int* __restrict__ cnt, const int* __restrict__ boff,
                           int* __restrict__ rowptr, int n) {
    __shared__ int sm[256];
    int i = blockIdx.x * 256 + threadIdx.x;
    int v = (i < n) ? cnt[i] : 0;
    sm[threadIdx.x] = v;
    __syncthreads();
    for (int off = 1; off < 256; off <<= 1) {
        int u = (threadIdx.x >= off) ? sm[threadIdx.x - off] : 0;
        __syncthreads();
        sm[threadIdx.x] += u;
        __syncthreads();
    }
    int incl = sm[threadIdx.x];
    int excl = incl - v;
    if (i < n) rowptr[i] = boff[blockIdx.x] + excl;
    if (i == n - 1) rowptr[n] = boff[blockIdx.x] + incl;  // == E
}

__global__ void scatter_kernel(const int* __restrict__ src, const int* __restrict__ dst,
                               const int* __restrict__ rowptr, int* __restrict__ cursor,
                               int* __restrict__ esrc, int e) {
    int i = blockIdx.x * blockDim.x + threadIdx.x;
    if (i < e) {
        int d = dst[i];
        int p = atomicAdd(&cursor[d], 1);
        esrc[rowptr[d] + p] = src[i];
    }
}

// ---------------------------------------------------------------------------
// LDS-tiled GEMM + fused attention-logit epilogue.
//   Outb (bf16-packed)  = RNE(X @ W)                [N, FOUT/2 uints]
//   alS[n,h] = sum_c h[n,h,c]*a_src[h,c]  (fp32, exact — from acc registers)
//   alD[n,h] = sum_c h[n,h,c]*a_dst[h,c]
// No fp32 h output: the gather uses bf16; logits use the fused fp32 path.
// ---------------------------------------------------------------------------
template <int FOUT, int H>
__global__ __launch_bounds__(256) void gemm_tiled(const float* __restrict__ X,
                                                  const float* __restrict__ Wm,
                                                  const float* __restrict__ a_s,
                                                  const float* __restrict__ a_d,
                                                  float* __restrict__ alS,
                                                  float* __restrict__ alD,
                                                  uint32* __restrict__ Outb, int n) {
    constexpr int K   = 128;
    constexpr int KC  = 32;
    constexpr int MT  = 128;
    constexpr int CPT = FOUT / 16;            // 8 (FOUT=128) or 2 (FOUT=32)
    constexpr int C   = FOUT / H;             // 32
    constexpr int TPH = 16 / H;               // tx-threads per head: 4 or 16
    __shared__ float As[KC][MT + 1];
    __shared__ float Bs[KC][FOUT];

    const int t   = threadIdx.x;
    const int tx  = t & 15;
    const int ty  = t >> 4;
    const int row0 = blockIdx.x * MT;

    float acc[8][CPT];
#pragma unroll
    for (int i = 0; i < 8; ++i)
#pragma unroll
        for (int j = 0; j < CPT; ++j) acc[i][j] = 0.f;

    for (int kc = 0; kc < K; kc += KC) {
#pragma unroll
        for (int i = 0; i < 4; ++i) {
            const int l  = t + i * 256;
            const int ar = l >> 3;
            const int af = l & 7;
            int grow = row0 + ar;
            if (grow >= n) grow = n - 1;
            const float4 v = *(const float4*)(X + (size_t)grow * K + kc + af * 4);
            As[af * 4 + 0][ar] = v.x;
            As[af * 4 + 1][ar] = v.y;
            As[af * 4 + 2][ar] = v.z;
            As[af * 4 + 3][ar] = v.w;
        }
        constexpr int BF4 = KC * FOUT / 4;
#pragma unroll
        for (int i = 0; i < BF4 / 256; ++i) {
            const int l   = t + i * 256;
            const int br  = l / (FOUT / 4);
            const int bc4 = l % (FOUT / 4);
            const float4 v = *(const float4*)(Wm + (size_t)(kc + br) * FOUT + bc4 * 4);
            *(float4*)&Bs[br][bc4 * 4] = v;
        }
        __syncthreads();

#pragma unroll 8
        for (int k = 0; k < KC; ++k) {
            float a[8], b[CPT];
#pragma unroll
            for (int i = 0; i < 8; ++i) a[i] = As[k][ty * 8 + i];
#pragma unroll
            for (int j = 0; j < CPT; ++j) b[j] = Bs[k][tx * CPT + j];
#pragma unroll
            for (int i = 0; i < 8; ++i)
#pragma unroll
                for (int j = 0; j < CPT; ++j)
                    acc[i][j] = fmaf(a[i], b[j], acc[i][j]);
        }
        __syncthreads();
    }

    // ---- fused al epilogue: my cols all belong to head h ----
    const int h     = tx / TPH;
    const int cbase = (tx % TPH) * CPT;       // col offset within head
    float av[CPT], dv[CPT];
#pragma unroll
    for (int j = 0; j < CPT; ++j) {
        av[j] = a_s[h * C + cbase + j];
        dv[j] = a_d[h * C + cbase + j];
    }

#pragma unroll
    for (int i = 0; i < 8; ++i) {
        const int grow = row0 + ty * 8 + i;
        // bf16 store
        if (grow < n) {
            uint32* bp = Outb + ((size_t)grow * FOUT + tx * CPT) / 2;
            if constexpr (CPT == 8) {
                uint4 pb;
                pb.x = packbf2(acc[i][0], acc[i][1]);
                pb.y = packbf2(acc[i][2], acc[i][3]);
                pb.z = packbf2(acc[i][4], acc[i][5]);
                pb.w = packbf2(acc[i][6], acc[i][7]);
                *(uint4*)bp = pb;
            } else {
                *bp = packbf2(acc[i][0], acc[i][1]);
            }
        }
        // partial logit dots + reduce across the TPH lanes sharing this head
        float ps = 0.f, pd = 0.f;
#pragma unroll
        for (int j = 0; j < CPT; ++j) {
            ps = fmaf(acc[i][j], av[j], ps);
            pd = fmaf(acc[i][j], dv[j], pd);
        }
#pragma unroll
        for (int off = 1; off < TPH; off <<= 1) {
            ps += __shfl_xor(ps, off);
            pd += __shfl_xor(pd, off);
        }
        if ((tx % TPH) == 0 && grow < n) {
            alS[(size_t)grow * H + h] = ps;
            alD[(size_t)grow * H + h] = pd;
        }
    }
}

// ---------------------------------------------------------------------------
// wave-per-destination aggregation (no-max softmax, bf16 gather) + BN + ELU
//   Out[d, :] = elu(bn( sum_e softmax(e)_e * h[src_e, :] + bias ))
// Logits are bounded (|e| <~ 10): exp() without max subtraction is safe and
// mathematically identical to max-subtracted softmax.
// Phase-2 (H=4): 4 edges/iteration, wave-uniform src -> readfirstlane ->
// SGPR base + lane offset (no vector 64-bit address arithmetic).
// Phase-2 (H=1): 4 edges/iteration via 16-lane groups (row is only 64 B).
// ---------------------------------------------------------------------------
template <int H, int C>
__global__ __launch_bounds__(256) void gat_aggregate(
    const uint32* __restrict__ Hb,            // bf16-packed h, row = H*C/2 uints
    const int* __restrict__ rowptr, const int* __restrict__ esrc,
    const float* __restrict__ alS, const float* __restrict__ alD,
    const float* __restrict__ bias, const float* __restrict__ gamma,
    const float* __restrict__ beta, const float* __restrict__ bnmean,
    const float* __restrict__ bnvar, float* __restrict__ Out, int n) {
    constexpr int F  = H * C;                 // 128 or 32
    constexpr int RW = F / 2;                 // uints per row: 64 or 16
    constexpr int NW = 4;
    // stride 68: head-plane h starts at bank 4h (68*h mod 32 = 4h) -> the 4
    // simultaneous b128 reads hit disjoint bank quads; slots 64..67 = zero pad.
    __shared__ __align__(16) int   s_src[NW][68];
    __shared__ __align__(16) float s_ex[NW][H][68];

    const int wave = threadIdx.x >> 6;
    const int lane = threadIdx.x & 63;
    const int d    = blockIdx.x * NW + wave;
    if (d >= n) return;                       // only wave-level barriers below

    if (lane < 4) {
        s_src[wave][64 + lane] = 0;
#pragma unroll
        for (int h = 0; h < H; ++h) s_ex[wave][h][64 + lane] = 0.f;
    }
    __builtin_amdgcn_wave_barrier();

    const int beg = rowptr[d], end = rowptr[d + 1];
    float al_d[H], sl[H];
#pragma unroll
    for (int h = 0; h < H; ++h) {
        al_d[h] = alD[(size_t)d * H + h];
        sl[h]   = 0.f;
    }
    float acc0 = 0.f, acc1 = 0.f;
    const int head = (H == 4) ? (lane >> 4) : 0;

    for (int base = beg; base < end; base += 64) {
        const int j   = base + lane;
        const bool act = (j < end);
        int sj = 0;
        float ex[H];
        if (act) {
            sj = esrc[j];
            if constexpr (H == 4) {
                float4 av = *(const float4*)(alS + (size_t)sj * 4);
                float t0 = av.x + al_d[0], t1 = av.y + al_d[1];
                float t2 = av.z + al_d[2], t3 = av.w + al_d[3];
                t0 = t0 > 0.f ? t0 : 0.2f * t0;
                t1 = t1 > 0.f ? t1 : 0.2f * t1;
                t2 = t2 > 0.f ? t2 : 0.2f * t2;
                t3 = t3 > 0.f ? t3 : 0.2f * t3;
                ex[0] = __expf(t0); ex[1] = __expf(t1);
                ex[2] = __expf(t2); ex[3] = __expf(t3);
            } else {
                float t0 = alS[sj] + al_d[0];
                t0 = t0 > 0.f ? t0 : 0.2f * t0;
                ex[0] = __expf(t0);
            }
        } else {
#pragma unroll
            for (int h = 0; h < H; ++h) ex[h] = 0.f;
        }
#pragma unroll
        for (int h = 0; h < H; ++h) {
            s_ex[wave][h][lane] = ex[h];
            sl[h] += ex[h];
        }
        s_src[wave][lane] = sj;
        __builtin_amdgcn_wave_barrier();

        const int cc = min(64, end - base);
        if constexpr (H == 4) {
            for (int jj = 0; jj < cc; jj += 4) {
                const int4   s4 = *(const int4*)&s_src[wave][jj];     // broadcast
                const float4 w4 = *(const float4*)&s_ex[wave][head][jj];
                const int b0 = __builtin_amdgcn_readfirstlane(s4.x);
                const int b1 = __builtin_amdgcn_readfirstlane(s4.y);
                const int b2 = __builtin_amdgcn_readfirstlane(s4.z);
                const int b3 = __builtin_amdgcn_readfirstlane(s4.w);
                const uint32 v0 = Hb[(size_t)b0 * RW + lane];  // SGPR base + voffset
                const uint32 v1 = Hb[(size_t)b1 * RW + lane];
                const uint32 v2 = Hb[(size_t)b2 * RW + lane];
                const uint32 v3 = Hb[(size_t)b3 * RW + lane];
                acc0 = fmaf(bf_lo(v0), w4.x, acc0); acc1 = fmaf(bf_hi(v0), w4.x, acc1);
                acc0 = fmaf(bf_lo(v1), w4.y, acc0); acc1 = fmaf(bf_hi(v1), w4.y, acc1);
                acc0 = fmaf(bf_lo(v2), w4.z, acc0); acc1 = fmaf(bf_hi(v2), w4.z, acc1);
                acc0 = fmaf(bf_lo(v3), w4.w, acc0); acc1 = fmaf(bf_hi(v3), w4.w, acc1);
            }
        } else {
            const int g  = lane >> 4;      // edge sub-slot
            const int li = lane & 15;      // uint within 16-uint row
            for (int jj = 0; jj < cc; jj += 4) {
                const int   idx = jj + g;              // <= 66, inside padding
                const int   sj2 = s_src[wave][idx];
                const float w   = s_ex[wave][0][idx];  // 0 beyond cc
                const uint32 v  = Hb[(size_t)sj2 * RW + li];
                acc0 = fmaf(bf_lo(v), w, acc0);
                acc1 = fmaf(bf_hi(v), w, acc1);
            }
        }
        __builtin_amdgcn_wave_barrier();
    }

    // reduce exp-sums across the wave (inactive lanes contributed 0)
#pragma unroll
    for (int h = 0; h < H; ++h) {
#pragma unroll
        for (int off = 32; off > 0; off >>= 1) sl[h] += __shfl_xor(sl[h], off);
    }
    float sh;
    if constexpr (H == 4) {
        float a = (head & 1) ? sl[1] : sl[0];
        float b = (head & 1) ? sl[3] : sl[2];
        sh = (head & 2) ? b : a;
    } else {
        sh = sl[0];
        // combine the 4 edge sub-slot groups' partial accumulators
        acc0 += __shfl_xor(acc0, 16); acc0 += __shfl_xor(acc0, 32);
        acc1 += __shfl_xor(acc1, 16); acc1 += __shfl_xor(acc1, 32);
    }

    const float inv = 1.f / (sh + 1e-16f);
    const int li  = (F == 128) ? lane : (lane & 15);
    const int c0 = 2 * li, c1 = 2 * li + 1;
    const bool wr = (F == 128) || (lane < 16);
    if (wr) {
        float o0 = acc0 * inv, o1 = acc1 * inv;
        float y0 = (o0 + bias[c0] - bnmean[c0]) * rsqrtf(bnvar[c0] + 1e-5f) * gamma[c0] + beta[c0];
        float y1 = (o1 + bias[c1] - bnmean[c1]) * rsqrtf(bnvar[c1] + 1e-5f) * gamma[c1] + beta[c1];
        y0 = y0 > 0.f ? y0 : expm1f(y0);
        y1 = y1 > 0.f ? y1 : expm1f(y1);
        *(float2*)(Out + (size_t)d * F + c0) = make_float2(y0, y1);
    }
}

// ---------------------------------------------------------------------------
// classifier: out[n, 10] = H3[n, 32] @ Wc[32, 10] + bc
// ---------------------------------------------------------------------------
__global__ void classifier_kernel(const float* __restrict__ H3, const float* __restrict__ Wc,
                                  const float* __restrict__ bc, float* __restrict__ out, int n) {
    int t  = blockIdx.x * blockDim.x + threadIdx.x;
    int ni = t / NCLS, c = t % NCLS;
    if (ni >= n) return;
    const float* row = H3 + (size_t)ni * HID;
    float a = bc[c];
#pragma unroll
    for (int k = 0; k < HID; ++k) a = fmaf(row[k], Wc[k * NCLS + c], a);
    out[(size_t)ni * NCLS + c] = a;
}

// ---------------------------------------------------------------------------
// launch
// ---------------------------------------------------------------------------
static inline char* align256(char* p) {
    return (char*)(((uintptr_t)p + 255) & ~(uintptr_t)255);
}

extern "C" void kernel_launch(void* const* d_in, const int* in_sizes, int n_in,
                              void* d_out, int out_size, void* d_ws, size_t ws_size,
                              hipStream_t stream) {
    const float* x  = (const float*)d_in[0];
    const int*   ei = (const int*)d_in[1];
    const int N = in_sizes[0] / FIN;
    const int E = in_sizes[1] / 2;
    const int* src = ei;
    const int* dst = ei + E;

    const float *W0 = (const float*)d_in[2],  *as0 = (const float*)d_in[3],
                *ad0 = (const float*)d_in[4], *b0 = (const float*)d_in[5],
                *g0 = (const float*)d_in[6],  *bt0 = (const float*)d_in[7],
                *m0 = (const float*)d_in[8],  *v0 = (const float*)d_in[9];
    const float *W1 = (const float*)d_in[10], *as1 = (const float*)d_in[11],
                *ad1 = (const float*)d_in[12],*b1 = (const float*)d_in[13],
                *g1 = (const float*)d_in[14], *bt1 = (const float*)d_in[15],
                *m1 = (const float*)d_in[16], *v1 = (const float*)d_in[17];
    const float *W2 = (const float*)d_in[18], *as2 = (const float*)d_in[19],
                *ad2 = (const float*)d_in[20],*b2 = (const float*)d_in[21],
                *g2 = (const float*)d_in[22], *bt2 = (const float*)d_in[23],
                *m2 = (const float*)d_in[24], *v2 = (const float*)d_in[25];
    const float *Wc = (const float*)d_in[26], *bc = (const float*)d_in[27];
    float* out = (float*)d_out;

    // workspace carve
    char* p = (char*)d_ws;
    uint32* Abf = (uint32*)p;   p = align256(p + (size_t)N * FIN * 2);   // gemm out bf16
    float* B = (float*)p;       p = align256(p + (size_t)N * FIN * 4);   // layer act out
    float* alS = (float*)p;     p = align256(p + (size_t)N * NHEADS * 4);
    float* alD = (float*)p;     p = align256(p + (size_t)N * NHEADS * 4);
    int* cnt = (int*)p;         p = align256(p + (size_t)N * 4);
    int* cursor = (int*)p;      p = align256(p + (size_t)N * 4);
    int* rowptr = (int*)p;      p = align256(p + (size_t)(N + 1) * 4);
    int* esrc = (int*)p;        p = align256(p + (size_t)E * 4);
    int* bsum = (int*)p;        p = align256(p + 512 * 4);
    int* boff = (int*)p;        p = align256(p + 512 * 4);
    (void)ws_size; (void)n_in; (void)out_size;

    const int NB = (N + 255) / 256;

    // ---- CSR build (once; shared by all 3 layers) ----
    zero_i32<<<NB, 256, 0, stream>>>(cnt, N);
    zero_i32<<<NB, 256, 0, stream>>>(cursor, N);
    hist_kernel<<<(E + 255) / 256, 256, 0, stream>>>(dst, cnt, E);
    scan_block_sums<<<NB, 256, 0, stream>>>(cnt, bsum, N);
    scan_single<<<1, 512, 0, stream>>>(bsum, boff, NB);
    scan_final<<<NB, 256, 0, stream>>>(cnt, boff, rowptr, N);
    scatter_kernel<<<(E + 255) / 256, 256, 0, stream>>>(src, dst, rowptr, cursor, esrc, E);

    const int GB = (N + 127) / 128;

    // ---- layer 0 ----
    gemm_tiled<128, 4><<<GB, 256, 0, stream>>>(x, W0, as0, ad0, alS, alD, Abf, N);
    gat_aggregate<4, 32><<<(N + 3) / 4, 256, 0, stream>>>(Abf, rowptr, esrc, alS, alD,
                                                          b0, g0, bt0, m0, v0, B, N);
    // ---- layer 1 ----
    gemm_tiled<128, 4><<<GB, 256, 0, stream>>>(B, W1, as1, ad1, alS, alD, Abf, N);
    gat_aggregate<4, 32><<<(N + 3) / 4, 256, 0, stream>>>(Abf, rowptr, esrc, alS, alD,
                                                          b1, g1, bt1, m1, v1, B, N);
    // ---- layer 2 (single head, C=32) ----
    gemm_tiled<32, 1><<<GB, 256, 0, stream>>>(B, W2, as2, ad2, alS, alD, Abf, N);
    gat_aggregate<1, 32><<<(N + 3) / 4, 256, 0, stream>>>(Abf, rowptr, esrc, alS, alD,
                                                          b2, g2, bt2, m2, v2, B, N);
    // ---- classifier ----
    classifier_kernel<<<(N * NCLS + 255) / 256, 256, 0, stream>>>(B, Wc, bc, out, N);
}

// Round 5
// 602.984 us; speedup vs baseline: 1.9963x; 1.1047x over previous
//
#include <hip/hip_runtime.h>
#include <hip/hip_bf16.h>
#include <math.h>

// Problem constants (match reference setup_inputs)
#define NN   100000
#define NE   1600000
#define FIN  128
#define HID  32
#define NHEADS 4
#define NCLS 10

typedef unsigned int uint32;

__device__ __forceinline__ float bf_lo(uint32 v) {
    return __builtin_bit_cast(float, v << 16);
}
__device__ __forceinline__ float bf_hi(uint32 v) {
    return __builtin_bit_cast(float, v & 0xffff0000u);
}
__device__ __forceinline__ uint32 packbf2(float a, float b) {
    uint32 ua = __builtin_bit_cast(uint32, a);
    uint32 ub = __builtin_bit_cast(uint32, b);
    ua = (ua + 0x7fffu + ((ua >> 16) & 1u)) >> 16;          // RNE
    ub = (ub + 0x7fffu + ((ub >> 16) & 1u)) & 0xffff0000u;  // RNE, keep high
    return ua | ub;
}

// ---------------------------------------------------------------------------
// CSR build kernels
// ---------------------------------------------------------------------------
__global__ void zero_i32(int* __restrict__ p, int n) {
    int i = blockIdx.x * blockDim.x + threadIdx.x;
    if (i < n) p[i] = 0;
}

// histogram + per-edge rank in one pass: the atomic's return value IS the
// rank of edge j within its dst segment. 4 edges/thread for atomic ILP.
__global__ void hist_rank_kernel(const int* __restrict__ dst, int* __restrict__ cnt,
                                 int* __restrict__ rank, int e) {
    const int t0 = blockIdx.x * (blockDim.x * 4) + threadIdx.x;
    int d[4];
    bool a[4];
#pragma unroll
    for (int k = 0; k < 4; ++k) {
        const int j = t0 + k * 256;
        a[k] = (j < e);
        d[k] = a[k] ? dst[j] : 0;
    }
    int r[4];
#pragma unroll
    for (int k = 0; k < 4; ++k)
        if (a[k]) r[k] = atomicAdd(&cnt[d[k]], 1);
#pragma unroll
    for (int k = 0; k < 4; ++k) {
        const int j = t0 + k * 256;
        if (a[k]) rank[j] = r[k];
    }
}

__global__ void scan_block_sums(const int* __restrict__ cnt, int* __restrict__ bsum, int n) {
    __shared__ int sm[256];
    int i = blockIdx.x * 256 + threadIdx.x;
    int v = (i < n) ? cnt[i] : 0;
    sm[threadIdx.x] = v;
    __syncthreads();
    for (int off = 128; off > 0; off >>= 1) {
        if (threadIdx.x < off) sm[threadIdx.x] += sm[threadIdx.x + off];
        __syncthreads();
    }
    if (threadIdx.x == 0) bsum[blockIdx.x] = sm[0];
}

__global__ void scan_single(const int* __restrict__ bsum, int* __restrict__ boff, int nb) {
    __shared__ int sm[512];
    int t = threadIdx.x;
    int v = (t < nb) ? bsum[t] : 0;
    sm[t] = v;
    __syncthreads();
    for (int off = 1; off < 512; off <<= 1) {
        int u = (t >= off) ? sm[t - off] : 0;
        __syncthreads();
        sm[t] += u;
        __syncthreads();
    }
    if (t < nb) boff[t] = sm[t] - v;   // exclusive
}

__global__ void scan_final(const int* __restrict__ cnt, const int* __restrict__ boff,
                           int* __restrict__ rowptr, int n) {
    __shared__ int sm[256];
    int i = blockIdx.x * 256 + threadIdx.x;
    int v = (i < n) ? cnt[i] : 0;
    sm[threadIdx.x] = v;
    __syncthreads();
    for (int off = 1; off < 256; off <<= 1) {
        int u = (threadIdx.x >= off) ? sm[threadIdx.x - off] : 0;
        __syncthreads();
        sm[threadIdx.x] += u;
        __syncthreads();
    }
    int incl = sm[threadIdx.x];
    int excl = incl - v;
    if (i < n) rowptr[i] = boff[blockIdx.x] + excl;
    if (i == n - 1) rowptr[n] = boff[blockIdx.x] + incl;  // == E
}

// atomic-free scatter: position = rowptr[dst] + rank. 4 edges/thread.
__global__ void scatter_kernel(const int* __restrict__ src, const int* __restrict__ dst,
                               const int* __restrict__ rank, const int* __restrict__ rowptr,
                               int* __restrict__ esrc, int e) {
    const int t0 = blockIdx.x * (blockDim.x * 4) + threadIdx.x;
#pragma unroll
    for (int k = 0; k < 4; ++k) {
        const int j = t0 + k * 256;
        if (j < e) {
            const int d = dst[j];
            esrc[rowptr[d] + rank[j]] = src[j];
        }
    }
}

// ---------------------------------------------------------------------------
// LDS-tiled GEMM + fused attention-logit epilogue.
//   Outb (bf16-packed)  = RNE(X @ W)                [N, FOUT/2 uints]
//   alS[n,h] = sum_c h[n,h,c]*a_src[h,c]  (fp32, exact — from acc registers)
//   alD[n,h] = sum_c h[n,h,c]*a_dst[h,c]
// ---------------------------------------------------------------------------
template <int FOUT, int H>
__global__ __launch_bounds__(256) void gemm_tiled(const float* __restrict__ X,
                                                  const float* __restrict__ Wm,
                                                  const float* __restrict__ a_s,
                                                  const float* __restrict__ a_d,
                                                  float* __restrict__ alS,
                                                  float* __restrict__ alD,
                                                  uint32* __restrict__ Outb, int n) {
    constexpr int K   = 128;
    constexpr int KC  = 32;
    constexpr int MT  = 128;
    constexpr int CPT = FOUT / 16;            // 8 (FOUT=128) or 2 (FOUT=32)
    constexpr int C   = FOUT / H;             // 32
    constexpr int TPH = 16 / H;               // tx-threads per head: 4 or 16
    __shared__ float As[KC][MT + 1];
    __shared__ float Bs[KC][FOUT];

    const int t   = threadIdx.x;
    const int tx  = t & 15;
    const int ty  = t >> 4;
    const int row0 = blockIdx.x * MT;

    float acc[8][CPT];
#pragma unroll
    for (int i = 0; i < 8; ++i)
#pragma unroll
        for (int j = 0; j < CPT; ++j) acc[i][j] = 0.f;

    for (int kc = 0; kc < K; kc += KC) {
#pragma unroll
        for (int i = 0; i < 4; ++i) {
            const int l  = t + i * 256;
            const int ar = l >> 3;
            const int af = l & 7;
            int grow = row0 + ar;
            if (grow >= n) grow = n - 1;
            const float4 v = *(const float4*)(X + (size_t)grow * K + kc + af * 4);
            As[af * 4 + 0][ar] = v.x;
            As[af * 4 + 1][ar] = v.y;
            As[af * 4 + 2][ar] = v.z;
            As[af * 4 + 3][ar] = v.w;
        }
        constexpr int BF4 = KC * FOUT / 4;
#pragma unroll
        for (int i = 0; i < BF4 / 256; ++i) {
            const int l   = t + i * 256;
            const int br  = l / (FOUT / 4);
            const int bc4 = l % (FOUT / 4);
            const float4 v = *(const float4*)(Wm + (size_t)(kc + br) * FOUT + bc4 * 4);
            *(float4*)&Bs[br][bc4 * 4] = v;
        }
        __syncthreads();

#pragma unroll 8
        for (int k = 0; k < KC; ++k) {
            float a[8], b[CPT];
#pragma unroll
            for (int i = 0; i < 8; ++i) a[i] = As[k][ty * 8 + i];
#pragma unroll
            for (int j = 0; j < CPT; ++j) b[j] = Bs[k][tx * CPT + j];
#pragma unroll
            for (int i = 0; i < 8; ++i)
#pragma unroll
                for (int j = 0; j < CPT; ++j)
                    acc[i][j] = fmaf(a[i], b[j], acc[i][j]);
        }
        __syncthreads();
    }

    // ---- fused al epilogue: my cols all belong to head h ----
    const int h     = tx / TPH;
    const int cbase = (tx % TPH) * CPT;       // col offset within head
    float av[CPT], dv[CPT];
#pragma unroll
    for (int j = 0; j < CPT; ++j) {
        av[j] = a_s[h * C + cbase + j];
        dv[j] = a_d[h * C + cbase + j];
    }

#pragma unroll
    for (int i = 0; i < 8; ++i) {
        const int grow = row0 + ty * 8 + i;
        // bf16 store
        if (grow < n) {
            uint32* bp = Outb + ((size_t)grow * FOUT + tx * CPT) / 2;
            if constexpr (CPT == 8) {
                uint4 pb;
                pb.x = packbf2(acc[i][0], acc[i][1]);
                pb.y = packbf2(acc[i][2], acc[i][3]);
                pb.z = packbf2(acc[i][4], acc[i][5]);
                pb.w = packbf2(acc[i][6], acc[i][7]);
                *(uint4*)bp = pb;
            } else {
                *bp = packbf2(acc[i][0], acc[i][1]);
            }
        }
        // partial logit dots + reduce across the TPH lanes sharing this head
        float ps = 0.f, pd = 0.f;
#pragma unroll
        for (int j = 0; j < CPT; ++j) {
            ps = fmaf(acc[i][j], av[j], ps);
            pd = fmaf(acc[i][j], dv[j], pd);
        }
#pragma unroll
        for (int off = 1; off < TPH; off <<= 1) {
            ps += __shfl_xor(ps, off);
            pd += __shfl_xor(pd, off);
        }
        if ((tx % TPH) == 0 && grow < n) {
            alS[(size_t)grow * H + h] = ps;
            alD[(size_t)grow * H + h] = pd;
        }
    }
}

// ---------------------------------------------------------------------------
// wave-per-destination aggregation (no-max softmax, bf16 gather) + BN + ELU
// ---------------------------------------------------------------------------
template <int H, int C>
__global__ __launch_bounds__(256) void gat_aggregate(
    const uint32* __restrict__ Hb,            // bf16-packed h, row = H*C/2 uints
    const int* __restrict__ rowptr, const int* __restrict__ esrc,
    const float* __restrict__ alS, const float* __restrict__ alD,
    const float* __restrict__ bias, const float* __restrict__ gamma,
    const float* __restrict__ beta, const float* __restrict__ bnmean,
    const float* __restrict__ bnvar, float* __restrict__ Out, int n) {
    constexpr int F  = H * C;                 // 128 or 32
    constexpr int RW = F / 2;                 // uints per row: 64 or 16
    constexpr int NW = 4;
    // stride 68: head-plane h starts at bank 4h -> the 4 simultaneous b128
    // reads hit disjoint bank quads; slots 64..67 = zero pad.
    __shared__ __align__(16) int   s_src[NW][68];
    __shared__ __align__(16) float s_ex[NW][H][68];

    const int wave = threadIdx.x >> 6;
    const int lane = threadIdx.x & 63;
    const int d    = blockIdx.x * NW + wave;
    if (d >= n) return;                       // only wave-level barriers below

    if (lane < 4) {
        s_src[wave][64 + lane] = 0;
#pragma unroll
        for (int h = 0; h < H; ++h) s_ex[wave][h][64 + lane] = 0.f;
    }
    __builtin_amdgcn_wave_barrier();

    const int beg = rowptr[d], end = rowptr[d + 1];
    float al_d[H], sl[H];
#pragma unroll
    for (int h = 0; h < H; ++h) {
        al_d[h] = alD[(size_t)d * H + h];
        sl[h]   = 0.f;
    }
    float acc0 = 0.f, acc1 = 0.f;
    const int head = (H == 4) ? (lane >> 4) : 0;

    for (int base = beg; base < end; base += 64) {
        const int j   = base + lane;
        const bool act = (j < end);
        int sj = 0;
        float ex[H];
        if (act) {
            sj = esrc[j];
            if constexpr (H == 4) {
                float4 av = *(const float4*)(alS + (size_t)sj * 4);
                float t0 = av.x + al_d[0], t1 = av.y + al_d[1];
                float t2 = av.z + al_d[2], t3 = av.w + al_d[3];
                t0 = t0 > 0.f ? t0 : 0.2f * t0;
                t1 = t1 > 0.f ? t1 : 0.2f * t1;
                t2 = t2 > 0.f ? t2 : 0.2f * t2;
                t3 = t3 > 0.f ? t3 : 0.2f * t3;
                ex[0] = __expf(t0); ex[1] = __expf(t1);
                ex[2] = __expf(t2); ex[3] = __expf(t3);
            } else {
                float t0 = alS[sj] + al_d[0];
                t0 = t0 > 0.f ? t0 : 0.2f * t0;
                ex[0] = __expf(t0);
            }
        } else {
#pragma unroll
            for (int h = 0; h < H; ++h) ex[h] = 0.f;
        }
#pragma unroll
        for (int h = 0; h < H; ++h) {
            s_ex[wave][h][lane] = ex[h];
            sl[h] += ex[h];
        }
        s_src[wave][lane] = sj;
        __builtin_amdgcn_wave_barrier();

        const int cc = min(64, end - base);
        if constexpr (H == 4) {
            for (int jj = 0; jj < cc; jj += 4) {
                const int4   s4 = *(const int4*)&s_src[wave][jj];     // broadcast
                const float4 w4 = *(const float4*)&s_ex[wave][head][jj];
                const int b0 = __builtin_amdgcn_readfirstlane(s4.x);
                const int b1 = __builtin_amdgcn_readfirstlane(s4.y);
                const int b2 = __builtin_amdgcn_readfirstlane(s4.z);
                const int b3 = __builtin_amdgcn_readfirstlane(s4.w);
                const uint32 v0 = Hb[(size_t)b0 * RW + lane];  // SGPR base + voffset
                const uint32 v1 = Hb[(size_t)b1 * RW + lane];
                const uint32 v2 = Hb[(size_t)b2 * RW + lane];
                const uint32 v3 = Hb[(size_t)b3 * RW + lane];
                acc0 = fmaf(bf_lo(v0), w4.x, acc0); acc1 = fmaf(bf_hi(v0), w4.x, acc1);
                acc0 = fmaf(bf_lo(v1), w4.y, acc0); acc1 = fmaf(bf_hi(v1), w4.y, acc1);
                acc0 = fmaf(bf_lo(v2), w4.z, acc0); acc1 = fmaf(bf_hi(v2), w4.z, acc1);
                acc0 = fmaf(bf_lo(v3), w4.w, acc0); acc1 = fmaf(bf_hi(v3), w4.w, acc1);
            }
        } else {
            const int g  = lane >> 4;      // edge sub-slot
            const int li = lane & 15;      // uint within 16-uint row
            for (int jj = 0; jj < cc; jj += 4) {
                const int   idx = jj + g;              // <= 66, inside padding
                const int   sj2 = s_src[wave][idx];
                const float w   = s_ex[wave][0][idx];  // 0 beyond cc
                const uint32 v  = Hb[(size_t)sj2 * RW + li];
                acc0 = fmaf(bf_lo(v), w, acc0);
                acc1 = fmaf(bf_hi(v), w, acc1);
            }
        }
        __builtin_amdgcn_wave_barrier();
    }

    // reduce exp-sums across the wave (inactive lanes contributed 0)
#pragma unroll
    for (int h = 0; h < H; ++h) {
#pragma unroll
        for (int off = 32; off > 0; off >>= 1) sl[h] += __shfl_xor(sl[h], off);
    }
    float sh;
    if constexpr (H == 4) {
        float a = (head & 1) ? sl[1] : sl[0];
        float b = (head & 1) ? sl[3] : sl[2];
        sh = (head & 2) ? b : a;
    } else {
        sh = sl[0];
        acc0 += __shfl_xor(acc0, 16); acc0 += __shfl_xor(acc0, 32);
        acc1 += __shfl_xor(acc1, 16); acc1 += __shfl_xor(acc1, 32);
    }

    const float inv = 1.f / (sh + 1e-16f);
    const int li  = (F == 128) ? lane : (lane & 15);
    const int c0 = 2 * li, c1 = 2 * li + 1;
    const bool wr = (F == 128) || (lane < 16);
    if (wr) {
        float o0 = acc0 * inv, o1 = acc1 * inv;
        float y0 = (o0 + bias[c0] - bnmean[c0]) * rsqrtf(bnvar[c0] + 1e-5f) * gamma[c0] + beta[c0];
        float y1 = (o1 + bias[c1] - bnmean[c1]) * rsqrtf(bnvar[c1] + 1e-5f) * gamma[c1] + beta[c1];
        y0 = y0 > 0.f ? y0 : expm1f(y0);
        y1 = y1 > 0.f ? y1 : expm1f(y1);
        *(float2*)(Out + (size_t)d * F + c0) = make_float2(y0, y1);
    }
}

// ---------------------------------------------------------------------------
// classifier: out[n, 10] = H3[n, 32] @ Wc[32, 10] + bc
// ---------------------------------------------------------------------------
__global__ void classifier_kernel(const float* __restrict__ H3, const float* __restrict__ Wc,
                                  const float* __restrict__ bc, float* __restrict__ out, int n) {
    int t  = blockIdx.x * blockDim.x + threadIdx.x;
    int ni = t / NCLS, c = t % NCLS;
    if (ni >= n) return;
    const float* row = H3 + (size_t)ni * HID;
    float a = bc[c];
#pragma unroll
    for (int k = 0; k < HID; ++k) a = fmaf(row[k], Wc[k * NCLS + c], a);
    out[(size_t)ni * NCLS + c] = a;
}

// ---------------------------------------------------------------------------
// launch
// ---------------------------------------------------------------------------
static inline char* align256(char* p) {
    return (char*)(((uintptr_t)p + 255) & ~(uintptr_t)255);
}

extern "C" void kernel_launch(void* const* d_in, const int* in_sizes, int n_in,
                              void* d_out, int out_size, void* d_ws, size_t ws_size,
                              hipStream_t stream) {
    const float* x  = (const float*)d_in[0];
    const int*   ei = (const int*)d_in[1];
    const int N = in_sizes[0] / FIN;
    const int E = in_sizes[1] / 2;
    const int* src = ei;
    const int* dst = ei + E;

    const float *W0 = (const float*)d_in[2],  *as0 = (const float*)d_in[3],
                *ad0 = (const float*)d_in[4], *b0 = (const float*)d_in[5],
                *g0 = (const float*)d_in[6],  *bt0 = (const float*)d_in[7],
                *m0 = (const float*)d_in[8],  *v0 = (const float*)d_in[9];
    const float *W1 = (const float*)d_in[10], *as1 = (const float*)d_in[11],
                *ad1 = (const float*)d_in[12],*b1 = (const float*)d_in[13],
                *g1 = (const float*)d_in[14], *bt1 = (const float*)d_in[15],
                *m1 = (const float*)d_in[16], *v1 = (const float*)d_in[17];
    const float *W2 = (const float*)d_in[18], *as2 = (const float*)d_in[19],
                *ad2 = (const float*)d_in[20],*b2 = (const float*)d_in[21],
                *g2 = (const float*)d_in[22], *bt2 = (const float*)d_in[23],
                *m2 = (const float*)d_in[24], *v2 = (const float*)d_in[25];
    const float *Wc = (const float*)d_in[26], *bc = (const float*)d_in[27];
    float* out = (float*)d_out;

    // workspace carve
    char* p = (char*)d_ws;
    uint32* Abf = (uint32*)p;   p = align256(p + (size_t)N * FIN * 2);   // gemm out bf16
    float* B = (float*)p;       p = align256(p + (size_t)N * FIN * 4);   // layer act out
    float* alS = (float*)p;     p = align256(p + (size_t)N * NHEADS * 4);
    float* alD = (float*)p;     p = align256(p + (size_t)N * NHEADS * 4);
    int* cnt = (int*)p;         p = align256(p + (size_t)N * 4);
    int* rowptr = (int*)p;      p = align256(p + (size_t)(N + 1) * 4);
    int* rank = (int*)p;        p = align256(p + (size_t)E * 4);
    int* esrc = (int*)p;        p = align256(p + (size_t)E * 4);
    int* bsum = (int*)p;        p = align256(p + 512 * 4);
    int* boff = (int*)p;        p = align256(p + 512 * 4);
    (void)ws_size; (void)n_in; (void)out_size;

    const int NB = (N + 255) / 256;
    const int EB4 = (E + 1023) / 1024;   // 4 edges/thread kernels

    // ---- CSR build (once; shared by all 3 layers) ----
    zero_i32<<<NB, 256, 0, stream>>>(cnt, N);
    hist_rank_kernel<<<EB4, 256, 0, stream>>>(dst, cnt, rank, E);
    scan_block_sums<<<NB, 256, 0, stream>>>(cnt, bsum, N);
    scan_single<<<1, 512, 0, stream>>>(bsum, boff, NB);
    scan_final<<<NB, 256, 0, stream>>>(cnt, boff, rowptr, N);
    scatter_kernel<<<EB4, 256, 0, stream>>>(src, dst, rank, rowptr, esrc, E);

    const int GB = (N + 127) / 128;

    // ---- layer 0 ----
    gemm_tiled<128, 4><<<GB, 256, 0, stream>>>(x, W0, as0, ad0, alS, alD, Abf, N);
    gat_aggregate<4, 32><<<(N + 3) / 4, 256, 0, stream>>>(Abf, rowptr, esrc, alS, alD,
                                                          b0, g0, bt0, m0, v0, B, N);
    // ---- layer 1 ----
    gemm_tiled<128, 4><<<GB, 256, 0, stream>>>(B, W1, as1, ad1, alS, alD, Abf, N);
    gat_aggregate<4, 32><<<(N + 3) / 4, 256, 0, stream>>>(Abf, rowptr, esrc, alS, alD,
                                                          b1, g1, bt1, m1, v1, B, N);
    // ---- layer 2 (single head, C=32) ----
    gemm_tiled<32, 1><<<GB, 256, 0, stream>>>(B, W2, as2, ad2, alS, alD, Abf, N);
    gat_aggregate<1, 32><<<(N + 3) / 4, 256, 0, stream>>>(Abf, rowptr, esrc, alS, alD,
                                                          b2, g2, bt2, m2, v2, B, N);
    // ---- classifier ----
    classifier_kernel<<<(N * NCLS + 255) / 256, 256, 0, stream>>>(B, Wc, bc, out, N);
}